// Round 11
// baseline (137.069 us; speedup 1.0000x reference)
//
#include <hip/hip_runtime.h>
#include <math.h>

#define P 128
#define NP (P*P)
#define BATCH 4

typedef __attribute__((ext_vector_type(8))) short bf16x8;
typedef __attribute__((ext_vector_type(4))) float f32x4;

__device__ __forceinline__ float sigmoidf_(float x){ return 1.f/(1.f+__expf(-x)); }
__device__ __forceinline__ float tanhf_(float x){
  float ax = fabsf(x);
  float e = __expf(2.f*ax);
  float t = 1.f - 2.f/(e + 1.f);
  return copysignf(t, x);
}
__device__ __forceinline__ short f2bf(float f){
  unsigned u = __builtin_bit_cast(unsigned, f);
  u = (u + 0x7FFFu + ((u>>16)&1u)) >> 16;
  return (short)u;
}
__device__ __forceinline__ float bf2f(short s){
  unsigned u = ((unsigned)(unsigned short)s) << 16;
  return __builtin_bit_cast(float, u);
}

// ---------------- maxpool 2x2 stride 2: (B,32,256,256) planar -> (B,P,P,32) channels-last ----------------
__global__ void maxpool_cl_k(const float* __restrict__ x, float* __restrict__ xp){
  int idx = blockIdx.x*256 + threadIdx.x;
  if (idx >= BATCH*NP) return;
  int wp = idx & (P-1); int t = idx >> 7; int hp = t & (P-1); int b = t >> 7;
  const float* src = x + ((size_t)b*32*65536) + (size_t)(hp*2)*256 + wp*2;
  float m[32];
  #pragma unroll
  for (int c = 0; c < 32; c++){
    const float* s = src + (size_t)c*65536;
    m[c] = fmaxf(fmaxf(s[0], s[1]), fmaxf(s[256], s[257]));
  }
  float* dst = xp + (size_t)idx*32;
  #pragma unroll
  for (int q = 0; q < 8; q++) *(float4*)(dst + q*4) = *(float4*)(m + q*4);
}

// ---------------- weight prep: ALL tables in MFMA-fragment-major order ----------------
// gates layout (M-split chunks): [tap9][cbh2][mh2][cb2][mbl8][lane64][s8]
//   chunk (tap,cbh,mh) is contiguous 16KB; global MB = mh*8+mbl, CB = cbh*2+cb.
__global__ void wprep_all_k(const float* __restrict__ wg, const float* __restrict__ w1,
                            const float* __restrict__ w2, const float* __restrict__ wo1,
                            const float* __restrict__ wo2,
                            short* __restrict__ wA, short* __restrict__ wd1T,
                            short* __restrict__ wd2T, short* __restrict__ woT1,
                            short* __restrict__ woT2){
  int idx = blockIdx.x*256 + threadIdx.x;
  if (idx < 294912){
    int s = idx & 7; int l = (idx>>3) & 63; int mbl = (idx>>9) & 7;
    int cb = (idx>>12) & 1; int mh = (idx>>13) & 1; int cbh = (idx>>14) & 1;
    int tap = idx >> 15;
    int ln = l & 15, kg = l >> 4;
    int r = (mh*8 + mbl)*16 + ln; int ch = r >> 2, gate = r & 3;
    int cin = (cbh*2 + cb)*32 + kg*8 + s;
    wA[idx] = f2bf(wg[((size_t)(gate*64 + ch)*128 + cin)*9 + tap]);
    return;
  }
  idx -= 294912;
  if (idx < 18432){
    int s = idx & 7; int l = (idx>>3) & 63; int mb = (idx>>9) & 3; int tap = idx >> 11;
    int ln = l & 15, kg = l >> 4;
    int o = mb*16 + ln; int cin = kg*8 + s;
    wd1T[idx] = f2bf(w1[((size_t)(o*32 + cin))*9 + tap]);
    return;
  }
  idx -= 18432;
  if (idx < 36864){
    int s = idx & 7; int l = (idx>>3) & 63; int mb = (idx>>9) & 3;
    int cb = (idx>>11) & 1; int tap = idx >> 12;
    int ln = l & 15, kg = l >> 4;
    int o = mb*16 + ln; int cin = cb*32 + kg*8 + s;
    wd2T[idx] = f2bf(w2[((size_t)(o*64 + cin))*9 + tap]);
    return;
  }
  idx -= 36864;
  if (idx < 9216){
    int s = idx & 7; int l = (idx>>3) & 63; int mb = (idx>>9) & 1; int tap = idx >> 10;
    int ln = l & 15, kg = l >> 4;
    int o = mb*16 + ln; int cin = kg*8 + s;
    woT1[idx] = (o < 18) ? f2bf(wo1[((size_t)(o*32 + cin))*9 + tap]) : (short)0;
    return;
  }
  idx -= 9216;
  if (idx < 18432){
    int s = idx & 7; int l = (idx>>3) & 63; int mb = (idx>>9) & 1;
    int cb = (idx>>10) & 1; int tap = idx >> 11;
    int ln = l & 15, kg = l >> 4;
    int o = mb*16 + ln; int cin = cb*32 + kg*8 + s;
    woT2[idx] = (o < 18) ? f2bf(wo2[((size_t)(o*64 + cin))*9 + tap]) : (short)0;
  }
}

// ---------------- fused offset-conv + deformable conv (MFMA) + BN partial sums ----------------
template<int CIN, bool BNIN>
__global__ __launch_bounds__(256) void deform_fused_k(
    const float* __restrict__ incl, const float* __restrict__ bstats,
    const float* __restrict__ b_off,
    const short* __restrict__ woT, const short* __restrict__ wdT,
    float* __restrict__ outcl, float* __restrict__ part){
  const int HS = 14, NHP = HS*HS;
  const int ROWB = CIN*2;
  const int CG = CIN/8, CGS = (CIN==64)?3:2;
  const int PM = (CIN==64)?7:3;
  const int NCB = CIN/32;
  __shared__ short xt[NHP*CIN];
  __shared__ float off_lds[64][20];
  __shared__ float red_s[4][64], red_q[4][64];
  int tid = threadIdx.x;
  int tile = blockIdx.x, b = blockIdx.y;
  int tx0 = (tile & 15)*8, ty0 = (tile >> 4)*8;
  const float* inb = incl + (size_t)b*NP*CIN;
  for (int e = tid; e < NHP*CG; e += 256){
    int cg = e & (CG-1), p = e >> CGS;
    int hr = p/HS, wc = p - hr*HS;
    int gy = ty0 + hr - 3, gx = tx0 + wc - 3;
    union { short s[8]; bf16x8 v; } u;
    if (((unsigned)gy < P) && ((unsigned)gx < P)){
      const float* src = inb + ((size_t)gy*P + gx)*CIN + cg*8;
      float4 a = *(const float4*)src, bb = *(const float4*)(src+4);
      if (BNIN){
        int c = cg*8;
        a.x = fmaxf(a.x*bstats[c+0]+bstats[64+c+0], 0.f);
        a.y = fmaxf(a.y*bstats[c+1]+bstats[64+c+1], 0.f);
        a.z = fmaxf(a.z*bstats[c+2]+bstats[64+c+2], 0.f);
        a.w = fmaxf(a.w*bstats[c+3]+bstats[64+c+3], 0.f);
        bb.x = fmaxf(bb.x*bstats[c+4]+bstats[64+c+4], 0.f);
        bb.y = fmaxf(bb.y*bstats[c+5]+bstats[64+c+5], 0.f);
        bb.z = fmaxf(bb.z*bstats[c+6]+bstats[64+c+6], 0.f);
        bb.w = fmaxf(bb.w*bstats[c+7]+bstats[64+c+7], 0.f);
      }
      u.s[0]=f2bf(a.x); u.s[1]=f2bf(a.y); u.s[2]=f2bf(a.z); u.s[3]=f2bf(a.w);
      u.s[4]=f2bf(bb.x); u.s[5]=f2bf(bb.y); u.s[6]=f2bf(bb.z); u.s[7]=f2bf(bb.w);
    } else {
      #pragma unroll
      for (int j = 0; j < 8; j++) u.s[j] = 0;
    }
    *(bf16x8*)((char*)xt + p*ROWB + ((cg*16) ^ ((p & PM)<<4))) = u.v;
  }
  __syncthreads();

  int lane = tid & 63, wid = tid >> 6;
  int kg = lane >> 4, ln = lane & 15;
  int py = ty0 + wid*2 + (ln>>3), pxg = tx0 + (ln&7);
  int pl = wid*16 + ln;

  {
    f32x4 acc_o[2];
    acc_o[0] = (f32x4){0.f,0.f,0.f,0.f};
    acc_o[1] = (f32x4){0.f,0.f,0.f,0.f};
    #pragma unroll
    for (int tap = 0; tap < 9; tap++){
      int ky = tap/3, kx = tap - (tap/3)*3;
      int lr = wid*2 + (ln>>3) + ky + 2;
      int lc = (ln&7) + kx + 2;
      int p = lr*HS + lc;
      #pragma unroll
      for (int cb = 0; cb < NCB; cb++){
        bf16x8 bfv = *(const bf16x8*)((const char*)xt + p*ROWB + (((cb*64) + kg*16) ^ ((p & PM)<<4)));
        bf16x8 af0 = *(const bf16x8*)(woT + ((size_t)((tap*NCB + cb)*2 + 0)*512 + lane*8));
        bf16x8 af1 = *(const bf16x8*)(woT + ((size_t)((tap*NCB + cb)*2 + 1)*512 + lane*8));
        acc_o[0] = __builtin_amdgcn_mfma_f32_16x16x32_bf16(af0, bfv, acc_o[0], 0, 0, 0);
        acc_o[1] = __builtin_amdgcn_mfma_f32_16x16x32_bf16(af1, bfv, acc_o[1], 0, 0, 0);
      }
    }
    #pragma unroll
    for (int mf = 0; mf < 2; mf++){
      #pragma unroll
      for (int j = 0; j < 4; j++){
        int o = mf*16 + kg*4 + j;
        if (o < 18) off_lds[pl][o] = acc_o[mf][j] + b_off[o];
      }
    }
  }
  __syncthreads();

  f32x4 acc[4];
  #pragma unroll
  for (int mf = 0; mf < 4; mf++) acc[mf] = (f32x4){0.f,0.f,0.f,0.f};

  for (int tap = 0; tap < 9; tap++){
    float dy = off_lds[pl][tap], dx = off_lds[pl][9+tap];
    float ys = (float)(py + tap/3 - 1) + dy;
    float xs = (float)(pxg + tap%3 - 1) + dx;
    float y0f = floorf(ys), x0f = floorf(xs);
    float wy1 = ys - y0f, wx1 = xs - x0f;
    float wy0 = 1.f - wy1, wx0 = 1.f - wx1;
    int y0 = (int)y0f, x0 = (int)x0f;
    bool v0y = ((unsigned)y0 < P), v1y = ((unsigned)(y0+1) < P);
    bool v0x = ((unsigned)x0 < P), v1x = ((unsigned)(x0+1) < P);
    float w00 = (v0y && v0x) ? wy0*wx0 : 0.f;
    float w01 = (v0y && v1x) ? wy0*wx1 : 0.f;
    float w10 = (v1y && v0x) ? wy1*wx0 : 0.f;
    float w11 = (v1y && v1x) ? wy1*wx1 : 0.f;
    int ly0 = min(max(y0 - ty0 + 3, 0), HS-1);
    int ly1 = min(max(y0 + 1 - ty0 + 3, 0), HS-1);
    int lx0 = min(max(x0 - tx0 + 3, 0), HS-1);
    int lx1 = min(max(x0 + 1 - tx0 + 3, 0), HS-1);
    int p00 = ly0*HS + lx0, p01 = ly0*HS + lx1;
    int p10 = ly1*HS + lx0, p11 = ly1*HS + lx1;
    #pragma unroll
    for (int cb = 0; cb < NCB; cb++){
      int ko = (cb*32 + kg*8)*2;
      bf16x8 c00 = *(const bf16x8*)((const char*)xt + p00*ROWB + (ko ^ ((p00 & PM)<<4)));
      bf16x8 c01 = *(const bf16x8*)((const char*)xt + p01*ROWB + (ko ^ ((p01 & PM)<<4)));
      bf16x8 c10 = *(const bf16x8*)((const char*)xt + p10*ROWB + (ko ^ ((p10 & PM)<<4)));
      bf16x8 c11 = *(const bf16x8*)((const char*)xt + p11*ROWB + (ko ^ ((p11 & PM)<<4)));
      union { short s[8]; bf16x8 v; } bu;
      #pragma unroll
      for (int j = 0; j < 8; j++){
        float v = w00*bf2f(c00[j]) + w01*bf2f(c01[j]) + w10*bf2f(c10[j]) + w11*bf2f(c11[j]);
        bu.s[j] = f2bf(v);
      }
      #pragma unroll
      for (int mf = 0; mf < 4; mf++){
        bf16x8 af = *(const bf16x8*)(wdT + ((size_t)((tap*NCB + cb)*4 + mf)*512 + lane*8));
        acc[mf] = __builtin_amdgcn_mfma_f32_16x16x32_bf16(af, bu.v, acc[mf], 0, 0, 0);
      }
    }
  }
  #pragma unroll
  for (int mf = 0; mf < 4; mf++){
    float* dst = outcl + ((size_t)b*NP + (size_t)py*P + pxg)*64 + mf*16 + kg*4;
    *(f32x4*)dst = acc[mf];
  }

  #pragma unroll
  for (int mf = 0; mf < 4; mf++){
    #pragma unroll
    for (int j = 0; j < 4; j++){
      float s = acc[mf][j], q = s*s;
      #pragma unroll
      for (int o = 1; o < 16; o <<= 1){
        s += __shfl_xor(s, o);
        q += __shfl_xor(q, o);
      }
      if (ln == 0){
        int ch = mf*16 + kg*4 + j;
        red_s[wid][ch] = s;
        red_q[wid][ch] = q;
      }
    }
  }
  __syncthreads();
  int blk = b*256 + tile;
  if (tid < 128){
    int ch = tid & 63;
    float v = (tid < 64)
      ? (red_s[0][ch]+red_s[1][ch]+red_s[2][ch]+red_s[3][ch])
      : (red_q[0][ch]+red_q[1][ch]+red_q[2][ch]+red_q[3][ch]);
    part[(size_t)tid*1024 + blk] = v;
  }
}

// ---------------- BN finalize ----------------
__global__ void bnfinal2_k(const float* __restrict__ part, const float* __restrict__ g,
                           const float* __restrict__ be, float* __restrict__ stats){
  int ch = blockIdx.x;
  int tid = threadIdx.x;
  float S = 0.f, Q = 0.f;
  for (int i = tid; i < 1024; i += 256){
    S += part[(size_t)ch*1024 + i];
    Q += part[(size_t)(64+ch)*1024 + i];
  }
  __shared__ float rs[256], rq[256];
  rs[tid] = S; rq[tid] = Q;
  __syncthreads();
  for (int o = 128; o > 0; o >>= 1){
    if (tid < o){ rs[tid] += rs[tid+o]; rq[tid] += rq[tid+o]; }
    __syncthreads();
  }
  if (tid == 0){
    const float inv = 1.f/(float)(BATCH*NP);
    float mean = rs[0]*inv;
    float var = rq[0]*inv - mean*mean;
    float scale = rsqrtf(var + 1e-5f)*g[ch];
    stats[ch] = scale;
    stats[64+ch] = be[ch] - mean*scale;
  }
}

// h0 planar -> hcl channels-last bf16 (B,NP,64)
__global__ void h2cl_k(const float* __restrict__ h0, short* __restrict__ hcl){
  __shared__ float t[64][65];
  int b = blockIdx.y;
  int p0 = blockIdx.x*64;
  int pl = threadIdx.x & 63;
  int cq = threadIdx.x >> 6;
  const float* src = h0 + (size_t)b*64*NP + p0 + pl;
  #pragma unroll
  for (int i = 0; i < 16; i++)
    t[cq*16+i][pl] = src[(size_t)(cq*16+i)*NP];
  __syncthreads();
  int p = threadIdx.x >> 2, q = threadIdx.x & 3;
  short* dst = hcl + ((size_t)(b*NP + p0 + p))*64 + q*16;
  union { short s[8]; bf16x8 v; } o0, o1;
  #pragma unroll
  for (int i = 0; i < 8; i++){ o0.s[i] = f2bf(t[q*16+i][p]); o1.s[i] = f2bf(t[q*16+8+i][p]); }
  *(bf16x8*)dst = o0.v;
  *(bf16x8*)(dst+8) = o1.v;
}

// ---------------- gates conv (128->256) MFMA + fused BN2 + LSTM ----------------
// M-split: each block computes 128 gate-rows (mh half). Tile 16x8 px.
// LDS: B-halo 46KB + double-buffered 16KB A chunks = 78.8KB -> 2 blocks/CU.
// Pairs (mh=0,1) of the same tile are 8 apart in blockIdx.x -> same XCD (L2 B-sharing).
// block 512 = 8 waves: ct = wid&1 (64 rows), nh = wid>>1 (2 px-rows each).
__global__ __launch_bounds__(512, 4) void gates_mfma_k(
    const float* __restrict__ y2, const float* __restrict__ stats,
    const short* __restrict__ hcl, const float* __restrict__ c0,
    const short* __restrict__ wA, const float* __restrict__ bg,
    float* __restrict__ outh, float* __restrict__ outc){
  extern __shared__ short lds[];
  short* bs = lds;                  // 180 px x 256B (swizzled) = 46080 B
  short* abuf = lds + 180*128;      // 2 x 8192 shorts (16 KB each)
  int tid = threadIdx.x;
  int bx = blockIdx.x, b = blockIdx.y;
  int tile = (bx >> 4)*8 + (bx & 7);
  int mh = (bx >> 3) & 1;
  int tx0 = (tile & 7)*16, ty0 = (tile >> 3)*8;
  int lane = tid & 63, wid = tid >> 6;

  // ---- stage B tile with fused BN2 (y2 raw fp32) + hcl half
  for (int e = tid; e < 180*16; e += 512){
    int cg = e & 15, p = e >> 4;
    int hr = p/18, wc = p - hr*18;
    int gy = ty0 + hr - 1, gx = tx0 + wc - 1;
    union { short s[8]; bf16x8 v; } u;
    if (((unsigned)gy < P) && ((unsigned)gx < P)){
      if (cg < 8){
        const float* src = y2 + ((size_t)(b*NP) + (size_t)gy*P + gx)*64 + cg*8;
        float4 a = *(const float4*)src, b4 = *(const float4*)(src+4);
        int c = cg*8;
        u.s[0] = f2bf(fmaxf(a.x*stats[c+0]+stats[64+c+0], 0.f));
        u.s[1] = f2bf(fmaxf(a.y*stats[c+1]+stats[64+c+1], 0.f));
        u.s[2] = f2bf(fmaxf(a.z*stats[c+2]+stats[64+c+2], 0.f));
        u.s[3] = f2bf(fmaxf(a.w*stats[c+3]+stats[64+c+3], 0.f));
        u.s[4] = f2bf(fmaxf(b4.x*stats[c+4]+stats[64+c+4], 0.f));
        u.s[5] = f2bf(fmaxf(b4.y*stats[c+5]+stats[64+c+5], 0.f));
        u.s[6] = f2bf(fmaxf(b4.z*stats[c+6]+stats[64+c+6], 0.f));
        u.s[7] = f2bf(fmaxf(b4.w*stats[c+7]+stats[64+c+7], 0.f));
      } else {
        u.v = *(const bf16x8*)(hcl + ((size_t)(b*NP) + (size_t)gy*P + gx)*64 + (cg-8)*8);
      }
    } else {
      #pragma unroll
      for (int j = 0; j < 8; j++) u.s[j] = 0;
    }
    *(bf16x8*)((char*)bs + p*256 + ((cg*16) ^ ((p&7)<<4))) = u.v;
  }

  // ---- A chunk stager: chunk c (tap*2+cbh) for this mh -> abuf half bi (16KB linear)
  auto stageA = [&](int c, int bi){
    const short* g = wA + (size_t)(c*2 + mh)*8192;
    short* l = abuf + bi*8192;
    #pragma unroll
    for (int i = 0; i < 2; i++){
      int unit = (wid*2 + i)*64;
      __builtin_amdgcn_global_load_lds(
          (const __attribute__((address_space(1))) unsigned int*)(g + (size_t)(unit + lane)*8),
          (__attribute__((address_space(3))) unsigned int*)(l + (size_t)unit*8),
          16, 0, 0);
    }
  };

  stageA(0, 0);
  __syncthreads();   // B staged + chunk 0 landed

  int kg = lane >> 4, ln = lane & 15;
  int ct = wid & 1, nh = wid >> 1;
  f32x4 acc[4][2];
  #pragma unroll
  for (int mf = 0; mf < 4; mf++)
    #pragma unroll
    for (int rr = 0; rr < 2; rr++) acc[mf][rr] = (f32x4){0.f,0.f,0.f,0.f};

  for (int c = 0; c < 18; c++){
    int cur = c & 1;
    if (c + 1 < 18) stageA(c + 1, cur ^ 1);   // prefetch into idle buffer (full chunk to land)
    int tap = c >> 1, cbh = c & 1;
    int ky = tap/3, kx = tap - ky*3;
    const short* al = abuf + cur*8192;
    bf16x8 af[2][4];
    #pragma unroll
    for (int cbl = 0; cbl < 2; cbl++)
      #pragma unroll
      for (int mf = 0; mf < 4; mf++)
        af[cbl][mf] = *(const bf16x8*)(al + (size_t)((cbl*8 + ct*4 + mf))*512 + lane*8);
    #pragma unroll
    for (int cbl = 0; cbl < 2; cbl++){
      int cb = cbh*2 + cbl;
      #pragma unroll
      for (int rr = 0; rr < 2; rr++){
        int p = (nh*2 + rr + ky)*18 + ln + kx;
        bf16x8 bfv = *(const bf16x8*)((const char*)bs + p*256 + (((cb*64) + kg*16) ^ ((p&7)<<4)));
        #pragma unroll
        for (int mf = 0; mf < 4; mf++)
          acc[mf][rr] = __builtin_amdgcn_mfma_f32_16x16x32_bf16(af[cbl][mf], bfv, acc[mf][rr], 0, 0, 0);
      }
    }
    __syncthreads();   // chunk c+1 landed (vmcnt drain) + all reads of cur done
  }

  #pragma unroll
  for (int mf = 0; mf < 4; mf++){
    int ch = mh*32 + ct*16 + mf*4 + kg;
    float bi = bg[ch], bff = bg[64+ch], bo = bg[128+ch], bgv = bg[192+ch];
    #pragma unroll
    for (int rr = 0; rr < 2; rr++){
      int py = ty0 + nh*2 + rr, px = tx0 + ln;
      size_t pidx = ((size_t)(b*64 + ch))*NP + (size_t)py*P + px;
      f32x4 a = acc[mf][rr];
      float cv = sigmoidf_(a[1]+bff)*c0[pidx] + sigmoidf_(a[0]+bi)*tanhf_(a[3]+bgv);
      float hv = sigmoidf_(a[2]+bo)*tanhf_(cv);
      outh[pidx] = hv;
      outc[pidx] = cv;
    }
  }
}

extern "C" void kernel_launch(void* const* d_in, const int* in_sizes, int n_in,
                              void* d_out, int out_size, void* d_ws, size_t ws_size,
                              hipStream_t stream) {
  const float* x      = (const float*)d_in[0];
  const float* h0     = (const float*)d_in[1];
  const float* c0     = (const float*)d_in[2];
  const float* w_off1 = (const float*)d_in[3];
  const float* b_off1 = (const float*)d_in[4];
  const float* w1     = (const float*)d_in[5];
  const float* g1     = (const float*)d_in[6];
  const float* be1    = (const float*)d_in[7];
  const float* w_off2 = (const float*)d_in[8];
  const float* b_off2 = (const float*)d_in[9];
  const float* w2     = (const float*)d_in[10];
  const float* g2     = (const float*)d_in[11];
  const float* be2    = (const float*)d_in[12];
  const float* wg     = (const float*)d_in[13];
  const float* bg     = (const float*)d_in[14];

  float* ws     = (float*)d_ws;
  float* xpcl   = ws;                          // 2097152 (dead after deform32)
  short* hcl    = (short*)ws;                  // overlays xpcl: 4194304 shorts
  float* y1     = ws + 2097152;                // 4194304
  float* y2     = ws + 6291456;                // 4194304
  float* part   = ws + 10485760;               // 131072
  float* stats1 = ws + 10616832;               // 128
  float* stats2 = ws + 10616960;               // 128
  short* wA     = (short*)(ws + 10617088);     // 294912
  short* wd1T   = wA + 294912;                 // 18432
  short* wd2T   = wd1T + 18432;                // 36864
  short* woT1   = wd2T + 36864;                // 9216
  short* woT2   = woT1 + 9216;                 // 18432

  (void)hipFuncSetAttribute((const void*)gates_mfma_k,
                            hipFuncAttributeMaxDynamicSharedMemorySize, 78848);

  maxpool_cl_k<<<dim3((BATCH*NP + 255)/256), dim3(256), 0, stream>>>(x, xpcl);
  wprep_all_k<<<dim3((377856 + 255)/256), dim3(256), 0, stream>>>(
      wg, w1, w2, w_off1, w_off2, wA, wd1T, wd2T, woT1, woT2);

  deform_fused_k<32,false><<<dim3(256, BATCH), dim3(256), 0, stream>>>(
      xpcl, stats1, b_off1, woT1, wd1T, y1, part);
  // xpcl dead from here; hcl overlay becomes writable
  h2cl_k<<<dim3(NP/64, BATCH), dim3(256), 0, stream>>>(h0, hcl);
  bnfinal2_k<<<dim3(64), dim3(256), 0, stream>>>(part, g1, be1, stats1);

  deform_fused_k<64,true><<<dim3(256, BATCH), dim3(256), 0, stream>>>(
      y1, stats1, b_off2, woT2, wd2T, y2, part);
  bnfinal2_k<<<dim3(64), dim3(256), 0, stream>>>(part, g2, be2, stats2);

  float* outh = (float*)d_out;
  float* outc = outh + (size_t)BATCH*64*NP;
  gates_mfma_k<<<dim3(256, BATCH), dim3(512), 78848, stream>>>(
      y2, stats2, hcl, c0, wA, bg, outh, outc);
}

// Round 12
// 131.497 us; speedup vs baseline: 1.0424x; 1.0424x over previous
//
#include <hip/hip_runtime.h>
#include <math.h>

#define P 128
#define NP (P*P)
#define BATCH 4

typedef __attribute__((ext_vector_type(8))) short bf16x8;
typedef __attribute__((ext_vector_type(4))) float f32x4;

__device__ __forceinline__ float sigmoidf_(float x){ return 1.f/(1.f+__expf(-x)); }
__device__ __forceinline__ float tanhf_(float x){
  float ax = fabsf(x);
  float e = __expf(2.f*ax);
  float t = 1.f - 2.f/(e + 1.f);
  return copysignf(t, x);
}
__device__ __forceinline__ short f2bf(float f){
  unsigned u = __builtin_bit_cast(unsigned, f);
  u = (u + 0x7FFFu + ((u>>16)&1u)) >> 16;
  return (short)u;
}
__device__ __forceinline__ float bf2f(short s){
  unsigned u = ((unsigned)(unsigned short)s) << 16;
  return __builtin_bit_cast(float, u);
}

// ---------------- maxpool 2x2 stride 2: (B,32,256,256) planar -> (B,P,P,32) channels-last ----------------
__global__ void maxpool_cl_k(const float* __restrict__ x, float* __restrict__ xp){
  int idx = blockIdx.x*256 + threadIdx.x;
  if (idx >= BATCH*NP) return;
  int wp = idx & (P-1); int t = idx >> 7; int hp = t & (P-1); int b = t >> 7;
  const float* src = x + ((size_t)b*32*65536) + (size_t)(hp*2)*256 + wp*2;
  float m[32];
  #pragma unroll
  for (int c = 0; c < 32; c++){
    const float* s = src + (size_t)c*65536;
    m[c] = fmaxf(fmaxf(s[0], s[1]), fmaxf(s[256], s[257]));
  }
  float* dst = xp + (size_t)idx*32;
  #pragma unroll
  for (int q = 0; q < 8; q++) *(float4*)(dst + q*4) = *(float4*)(m + q*4);
}

// ---------------- weight prep: ALL tables in MFMA-fragment-major order ----------------
// gates: [tap9][cb4][mb16][lane64][s8] — chunk (tap,cb) contiguous 16KB.
__global__ void wprep_all_k(const float* __restrict__ wg, const float* __restrict__ w1,
                            const float* __restrict__ w2, const float* __restrict__ wo1,
                            const float* __restrict__ wo2,
                            short* __restrict__ wA, short* __restrict__ wd1T,
                            short* __restrict__ wd2T, short* __restrict__ woT1,
                            short* __restrict__ woT2){
  int idx = blockIdx.x*256 + threadIdx.x;
  if (idx < 294912){
    int s = idx & 7; int l = (idx>>3) & 63; int mb = (idx>>9) & 15;
    int cb = (idx>>13) & 3; int tap = idx >> 15;
    int ln = l & 15, kg = l >> 4;
    int r = mb*16 + ln; int ch = r >> 2, gate = r & 3;
    int cin = cb*32 + kg*8 + s;
    wA[idx] = f2bf(wg[((size_t)(gate*64 + ch)*128 + cin)*9 + tap]);
    return;
  }
  idx -= 294912;
  if (idx < 18432){
    int s = idx & 7; int l = (idx>>3) & 63; int mb = (idx>>9) & 3; int tap = idx >> 11;
    int ln = l & 15, kg = l >> 4;
    int o = mb*16 + ln; int cin = kg*8 + s;
    wd1T[idx] = f2bf(w1[((size_t)(o*32 + cin))*9 + tap]);
    return;
  }
  idx -= 18432;
  if (idx < 36864){
    int s = idx & 7; int l = (idx>>3) & 63; int mb = (idx>>9) & 3;
    int cb = (idx>>11) & 1; int tap = idx >> 12;
    int ln = l & 15, kg = l >> 4;
    int o = mb*16 + ln; int cin = cb*32 + kg*8 + s;
    wd2T[idx] = f2bf(w2[((size_t)(o*64 + cin))*9 + tap]);
    return;
  }
  idx -= 36864;
  if (idx < 9216){
    int s = idx & 7; int l = (idx>>3) & 63; int mb = (idx>>9) & 1; int tap = idx >> 10;
    int ln = l & 15, kg = l >> 4;
    int o = mb*16 + ln; int cin = kg*8 + s;
    woT1[idx] = (o < 18) ? f2bf(wo1[((size_t)(o*32 + cin))*9 + tap]) : (short)0;
    return;
  }
  idx -= 9216;
  if (idx < 18432){
    int s = idx & 7; int l = (idx>>3) & 63; int mb = (idx>>9) & 1;
    int cb = (idx>>10) & 1; int tap = idx >> 11;
    int ln = l & 15, kg = l >> 4;
    int o = mb*16 + ln; int cin = cb*32 + kg*8 + s;
    woT2[idx] = (o < 18) ? f2bf(wo2[((size_t)(o*64 + cin))*9 + tap]) : (short)0;
  }
}

// ---------------- fused offset-conv + deformable conv (MFMA) + BN partial sums ----------------
template<int CIN, bool BNIN>
__global__ __launch_bounds__(256) void deform_fused_k(
    const float* __restrict__ incl, const float* __restrict__ bstats,
    const float* __restrict__ b_off,
    const short* __restrict__ woT, const short* __restrict__ wdT,
    float* __restrict__ outcl, float* __restrict__ part){
  const int HS = 14, NHP = HS*HS;
  const int ROWB = CIN*2;
  const int CG = CIN/8, CGS = (CIN==64)?3:2;
  const int PM = (CIN==64)?7:3;
  const int NCB = CIN/32;
  __shared__ short xt[NHP*CIN];
  __shared__ float off_lds[64][20];
  __shared__ float red_s[4][64], red_q[4][64];
  int tid = threadIdx.x;
  int tile = blockIdx.x, b = blockIdx.y;
  int tx0 = (tile & 15)*8, ty0 = (tile >> 4)*8;
  const float* inb = incl + (size_t)b*NP*CIN;
  for (int e = tid; e < NHP*CG; e += 256){
    int cg = e & (CG-1), p = e >> CGS;
    int hr = p/HS, wc = p - hr*HS;
    int gy = ty0 + hr - 3, gx = tx0 + wc - 3;
    union { short s[8]; bf16x8 v; } u;
    if (((unsigned)gy < P) && ((unsigned)gx < P)){
      const float* src = inb + ((size_t)gy*P + gx)*CIN + cg*8;
      float4 a = *(const float4*)src, bb = *(const float4*)(src+4);
      if (BNIN){
        int c = cg*8;
        a.x = fmaxf(a.x*bstats[c+0]+bstats[64+c+0], 0.f);
        a.y = fmaxf(a.y*bstats[c+1]+bstats[64+c+1], 0.f);
        a.z = fmaxf(a.z*bstats[c+2]+bstats[64+c+2], 0.f);
        a.w = fmaxf(a.w*bstats[c+3]+bstats[64+c+3], 0.f);
        bb.x = fmaxf(bb.x*bstats[c+4]+bstats[64+c+4], 0.f);
        bb.y = fmaxf(bb.y*bstats[c+5]+bstats[64+c+5], 0.f);
        bb.z = fmaxf(bb.z*bstats[c+6]+bstats[64+c+6], 0.f);
        bb.w = fmaxf(bb.w*bstats[c+7]+bstats[64+c+7], 0.f);
      }
      u.s[0]=f2bf(a.x); u.s[1]=f2bf(a.y); u.s[2]=f2bf(a.z); u.s[3]=f2bf(a.w);
      u.s[4]=f2bf(bb.x); u.s[5]=f2bf(bb.y); u.s[6]=f2bf(bb.z); u.s[7]=f2bf(bb.w);
    } else {
      #pragma unroll
      for (int j = 0; j < 8; j++) u.s[j] = 0;
    }
    *(bf16x8*)((char*)xt + p*ROWB + ((cg*16) ^ ((p & PM)<<4))) = u.v;
  }
  __syncthreads();

  int lane = tid & 63, wid = tid >> 6;
  int kg = lane >> 4, ln = lane & 15;
  int py = ty0 + wid*2 + (ln>>3), pxg = tx0 + (ln&7);
  int pl = wid*16 + ln;

  {
    f32x4 acc_o[2];
    acc_o[0] = (f32x4){0.f,0.f,0.f,0.f};
    acc_o[1] = (f32x4){0.f,0.f,0.f,0.f};
    #pragma unroll
    for (int tap = 0; tap < 9; tap++){
      int ky = tap/3, kx = tap - (tap/3)*3;
      int lr = wid*2 + (ln>>3) + ky + 2;
      int lc = (ln&7) + kx + 2;
      int p = lr*HS + lc;
      #pragma unroll
      for (int cb = 0; cb < NCB; cb++){
        bf16x8 bfv = *(const bf16x8*)((const char*)xt + p*ROWB + (((cb*64) + kg*16) ^ ((p & PM)<<4)));
        bf16x8 af0 = *(const bf16x8*)(woT + ((size_t)((tap*NCB + cb)*2 + 0)*512 + lane*8));
        bf16x8 af1 = *(const bf16x8*)(woT + ((size_t)((tap*NCB + cb)*2 + 1)*512 + lane*8));
        acc_o[0] = __builtin_amdgcn_mfma_f32_16x16x32_bf16(af0, bfv, acc_o[0], 0, 0, 0);
        acc_o[1] = __builtin_amdgcn_mfma_f32_16x16x32_bf16(af1, bfv, acc_o[1], 0, 0, 0);
      }
    }
    #pragma unroll
    for (int mf = 0; mf < 2; mf++){
      #pragma unroll
      for (int j = 0; j < 4; j++){
        int o = mf*16 + kg*4 + j;
        if (o < 18) off_lds[pl][o] = acc_o[mf][j] + b_off[o];
      }
    }
  }
  __syncthreads();

  f32x4 acc[4];
  #pragma unroll
  for (int mf = 0; mf < 4; mf++) acc[mf] = (f32x4){0.f,0.f,0.f,0.f};

  for (int tap = 0; tap < 9; tap++){
    float dy = off_lds[pl][tap], dx = off_lds[pl][9+tap];
    float ys = (float)(py + tap/3 - 1) + dy;
    float xs = (float)(pxg + tap%3 - 1) + dx;
    float y0f = floorf(ys), x0f = floorf(xs);
    float wy1 = ys - y0f, wx1 = xs - x0f;
    float wy0 = 1.f - wy1, wx0 = 1.f - wx1;
    int y0 = (int)y0f, x0 = (int)x0f;
    bool v0y = ((unsigned)y0 < P), v1y = ((unsigned)(y0+1) < P);
    bool v0x = ((unsigned)x0 < P), v1x = ((unsigned)(x0+1) < P);
    float w00 = (v0y && v0x) ? wy0*wx0 : 0.f;
    float w01 = (v0y && v1x) ? wy0*wx1 : 0.f;
    float w10 = (v1y && v0x) ? wy1*wx0 : 0.f;
    float w11 = (v1y && v1x) ? wy1*wx1 : 0.f;
    int ly0 = min(max(y0 - ty0 + 3, 0), HS-1);
    int ly1 = min(max(y0 + 1 - ty0 + 3, 0), HS-1);
    int lx0 = min(max(x0 - tx0 + 3, 0), HS-1);
    int lx1 = min(max(x0 + 1 - tx0 + 3, 0), HS-1);
    int p00 = ly0*HS + lx0, p01 = ly0*HS + lx1;
    int p10 = ly1*HS + lx0, p11 = ly1*HS + lx1;
    #pragma unroll
    for (int cb = 0; cb < NCB; cb++){
      int ko = (cb*32 + kg*8)*2;
      bf16x8 c00 = *(const bf16x8*)((const char*)xt + p00*ROWB + (ko ^ ((p00 & PM)<<4)));
      bf16x8 c01 = *(const bf16x8*)((const char*)xt + p01*ROWB + (ko ^ ((p01 & PM)<<4)));
      bf16x8 c10 = *(const bf16x8*)((const char*)xt + p10*ROWB + (ko ^ ((p10 & PM)<<4)));
      bf16x8 c11 = *(const bf16x8*)((const char*)xt + p11*ROWB + (ko ^ ((p11 & PM)<<4)));
      union { short s[8]; bf16x8 v; } bu;
      #pragma unroll
      for (int j = 0; j < 8; j++){
        float v = w00*bf2f(c00[j]) + w01*bf2f(c01[j]) + w10*bf2f(c10[j]) + w11*bf2f(c11[j]);
        bu.s[j] = f2bf(v);
      }
      #pragma unroll
      for (int mf = 0; mf < 4; mf++){
        bf16x8 af = *(const bf16x8*)(wdT + ((size_t)((tap*NCB + cb)*4 + mf)*512 + lane*8));
        acc[mf] = __builtin_amdgcn_mfma_f32_16x16x32_bf16(af, bu.v, acc[mf], 0, 0, 0);
      }
    }
  }
  #pragma unroll
  for (int mf = 0; mf < 4; mf++){
    float* dst = outcl + ((size_t)b*NP + (size_t)py*P + pxg)*64 + mf*16 + kg*4;
    *(f32x4*)dst = acc[mf];
  }

  #pragma unroll
  for (int mf = 0; mf < 4; mf++){
    #pragma unroll
    for (int j = 0; j < 4; j++){
      float s = acc[mf][j], q = s*s;
      #pragma unroll
      for (int o = 1; o < 16; o <<= 1){
        s += __shfl_xor(s, o);
        q += __shfl_xor(q, o);
      }
      if (ln == 0){
        int ch = mf*16 + kg*4 + j;
        red_s[wid][ch] = s;
        red_q[wid][ch] = q;
      }
    }
  }
  __syncthreads();
  int blk = b*256 + tile;
  if (tid < 128){
    int ch = tid & 63;
    float v = (tid < 64)
      ? (red_s[0][ch]+red_s[1][ch]+red_s[2][ch]+red_s[3][ch])
      : (red_q[0][ch]+red_q[1][ch]+red_q[2][ch]+red_q[3][ch]);
    part[(size_t)tid*1024 + blk] = v;
  }
}

// ---------------- BN finalize ----------------
__global__ void bnfinal2_k(const float* __restrict__ part, const float* __restrict__ g,
                           const float* __restrict__ be, float* __restrict__ stats){
  int ch = blockIdx.x;
  int tid = threadIdx.x;
  float S = 0.f, Q = 0.f;
  for (int i = tid; i < 1024; i += 256){
    S += part[(size_t)ch*1024 + i];
    Q += part[(size_t)(64+ch)*1024 + i];
  }
  __shared__ float rs[256], rq[256];
  rs[tid] = S; rq[tid] = Q;
  __syncthreads();
  for (int o = 128; o > 0; o >>= 1){
    if (tid < o){ rs[tid] += rs[tid+o]; rq[tid] += rq[tid+o]; }
    __syncthreads();
  }
  if (tid == 0){
    const float inv = 1.f/(float)(BATCH*NP);
    float mean = rs[0]*inv;
    float var = rq[0]*inv - mean*mean;
    float scale = rsqrtf(var + 1e-5f)*g[ch];
    stats[ch] = scale;
    stats[64+ch] = be[ch] - mean*scale;
  }
}

// h0 planar -> hcl channels-last bf16 (B,NP,64)
__global__ void h2cl_k(const float* __restrict__ h0, short* __restrict__ hcl){
  __shared__ float t[64][65];
  int b = blockIdx.y;
  int p0 = blockIdx.x*64;
  int pl = threadIdx.x & 63;
  int cq = threadIdx.x >> 6;
  const float* src = h0 + (size_t)b*64*NP + p0 + pl;
  #pragma unroll
  for (int i = 0; i < 16; i++)
    t[cq*16+i][pl] = src[(size_t)(cq*16+i)*NP];
  __syncthreads();
  int p = threadIdx.x >> 2, q = threadIdx.x & 3;
  short* dst = hcl + ((size_t)(b*NP + p0 + p))*64 + q*16;
  union { short s[8]; bf16x8 v; } o0, o1;
  #pragma unroll
  for (int i = 0; i < 8; i++){ o0.s[i] = f2bf(t[q*16+i][p]); o1.s[i] = f2bf(t[q*16+8+i][p]); }
  *(bf16x8*)dst = o0.v;
  *(bf16x8*)(dst+8) = o1.v;
}

// ---------------- gates conv (128->256) MFMA + fused BN2 + LSTM ----------------
// M=256/block, tile 16x8 px; 36 chunks of 16KB (tap,cb), double-buffered A with
// counted-vmcnt raw barriers (depth-2 prefetch pipeline). LDS 78.8KB -> 2 blocks/CU.
// block 512 = 8 waves: ct = wid>>1 (64 gate-rows), nh = wid&1 (4 px-rows -> 64 px).
__global__ __launch_bounds__(512, 4) void gates_mfma_k(
    const float* __restrict__ y2, const float* __restrict__ stats,
    const short* __restrict__ hcl, const float* __restrict__ c0,
    const short* __restrict__ wA, const float* __restrict__ bg,
    float* __restrict__ outh, float* __restrict__ outc){
  extern __shared__ short lds[];
  short* bs = lds;                  // 180 px x 256B (swizzled) = 46080 B
  short* abuf = lds + 180*128;      // 2 x 8192 shorts (16 KB each)
  int tid = threadIdx.x;
  int tile = blockIdx.x, b = blockIdx.y;
  int tx0 = (tile & 7)*16, ty0 = (tile >> 3)*8;
  int lane = tid & 63, wid = tid >> 6;

  // ---- stage B tile with fused BN2 (y2 raw fp32) + hcl half
  for (int e = tid; e < 180*16; e += 512){
    int cg = e & 15, p = e >> 4;
    int hr = p/18, wc = p - hr*18;
    int gy = ty0 + hr - 1, gx = tx0 + wc - 1;
    union { short s[8]; bf16x8 v; } u;
    if (((unsigned)gy < P) && ((unsigned)gx < P)){
      if (cg < 8){
        const float* src = y2 + ((size_t)(b*NP) + (size_t)gy*P + gx)*64 + cg*8;
        float4 a = *(const float4*)src, b4 = *(const float4*)(src+4);
        int c = cg*8;
        u.s[0] = f2bf(fmaxf(a.x*stats[c+0]+stats[64+c+0], 0.f));
        u.s[1] = f2bf(fmaxf(a.y*stats[c+1]+stats[64+c+1], 0.f));
        u.s[2] = f2bf(fmaxf(a.z*stats[c+2]+stats[64+c+2], 0.f));
        u.s[3] = f2bf(fmaxf(a.w*stats[c+3]+stats[64+c+3], 0.f));
        u.s[4] = f2bf(fmaxf(b4.x*stats[c+4]+stats[64+c+4], 0.f));
        u.s[5] = f2bf(fmaxf(b4.y*stats[c+5]+stats[64+c+5], 0.f));
        u.s[6] = f2bf(fmaxf(b4.z*stats[c+6]+stats[64+c+6], 0.f));
        u.s[7] = f2bf(fmaxf(b4.w*stats[c+7]+stats[64+c+7], 0.f));
      } else {
        u.v = *(const bf16x8*)(hcl + ((size_t)(b*NP) + (size_t)gy*P + gx)*64 + (cg-8)*8);
      }
    } else {
      #pragma unroll
      for (int j = 0; j < 8; j++) u.s[j] = 0;
    }
    *(bf16x8*)((char*)bs + p*256 + ((cg*16) ^ ((p&7)<<4))) = u.v;
  }

  // ---- A chunk stager: chunk c -> abuf half bi (16KB linear, 2 gload_lds/thread)
  auto stageA = [&](int c, int bi){
    const short* g = wA + (size_t)c*8192;
    short* l = abuf + bi*8192;
    #pragma unroll
    for (int i = 0; i < 2; i++){
      int unit = wid*2 + i;
      __builtin_amdgcn_global_load_lds(
          (const __attribute__((address_space(1))) unsigned int*)(g + (size_t)(unit*64 + lane)*8),
          (__attribute__((address_space(3))) unsigned int*)(l + (size_t)unit*512),
          16, 0, 0);
    }
  };

  stageA(0, 0);
  stageA(1, 1);
  __syncthreads();   // full drain: B + chunks 0,1 landed

  int kg = lane >> 4, ln = lane & 15;
  int ct = wid >> 1, nh = wid & 1;
  f32x4 acc[4][4];
  #pragma unroll
  for (int mf = 0; mf < 4; mf++)
    #pragma unroll
    for (int rr = 0; rr < 4; rr++) acc[mf][rr] = (f32x4){0.f,0.f,0.f,0.f};

  for (int c = 0; c < 36; c++){
    int cur = c & 1;
    int tap = c >> 2, cb = c & 3;
    int ky = tap/3, kx = tap - ky*3;
    const short* al = abuf + cur*8192;
    // all LDS reads for this chunk up front
    bf16x8 af[4], bf[4];
    #pragma unroll
    for (int mf = 0; mf < 4; mf++)
      af[mf] = *(const bf16x8*)(al + (size_t)(ct*4 + mf)*512 + lane*8);
    #pragma unroll
    for (int rr = 0; rr < 4; rr++){
      int p = (nh*4 + rr + ky)*18 + ln + kx;
      bf[rr] = *(const bf16x8*)((const char*)bs + p*256 + (((cb*64) + kg*16) ^ ((p&7)<<4)));
    }
    // BARRIER A: all waves done reading cur (lgkm only — no vmem drain)
    asm volatile("s_waitcnt lgkmcnt(0)" ::: "memory");
    __builtin_amdgcn_sched_barrier(0);
    __builtin_amdgcn_s_barrier();
    __builtin_amdgcn_sched_barrier(0);
    // prefetch chunk c+2 into cur (safe: everyone read it)
    if (c + 2 < 36) stageA(c + 2, cur);
    // pure-register MFMA block
    #pragma unroll
    for (int rr = 0; rr < 4; rr++)
      #pragma unroll
      for (int mf = 0; mf < 4; mf++)
        acc[mf][rr] = __builtin_amdgcn_mfma_f32_16x16x32_bf16(af[mf], bf[rr], acc[mf][rr], 0, 0, 0);
    // BARRIER B: chunk c+1 visible (counted vmcnt: allow c+2's 2 loads in flight)
    if (c + 2 < 36){
      asm volatile("s_waitcnt vmcnt(2)" ::: "memory");
    } else {
      asm volatile("s_waitcnt vmcnt(0)" ::: "memory");
    }
    __builtin_amdgcn_sched_barrier(0);
    __builtin_amdgcn_s_barrier();
    __builtin_amdgcn_sched_barrier(0);
  }

  #pragma unroll
  for (int mf = 0; mf < 4; mf++){
    int ch = ct*16 + mf*4 + kg;
    float bi = bg[ch], bff = bg[64+ch], bo = bg[128+ch], bgv = bg[192+ch];
    #pragma unroll
    for (int rr = 0; rr < 4; rr++){
      int py = ty0 + nh*4 + rr, px = tx0 + ln;
      size_t pidx = ((size_t)(b*64 + ch))*NP + (size_t)py*P + px;
      f32x4 a = acc[mf][rr];
      float cv = sigmoidf_(a[1]+bff)*c0[pidx] + sigmoidf_(a[0]+bi)*tanhf_(a[3]+bgv);
      float hv = sigmoidf_(a[2]+bo)*tanhf_(cv);
      outh[pidx] = hv;
      outc[pidx] = cv;
    }
  }
}

extern "C" void kernel_launch(void* const* d_in, const int* in_sizes, int n_in,
                              void* d_out, int out_size, void* d_ws, size_t ws_size,
                              hipStream_t stream) {
  const float* x      = (const float*)d_in[0];
  const float* h0     = (const float*)d_in[1];
  const float* c0     = (const float*)d_in[2];
  const float* w_off1 = (const float*)d_in[3];
  const float* b_off1 = (const float*)d_in[4];
  const float* w1     = (const float*)d_in[5];
  const float* g1     = (const float*)d_in[6];
  const float* be1    = (const float*)d_in[7];
  const float* w_off2 = (const float*)d_in[8];
  const float* b_off2 = (const float*)d_in[9];
  const float* w2     = (const float*)d_in[10];
  const float* g2     = (const float*)d_in[11];
  const float* be2    = (const float*)d_in[12];
  const float* wg     = (const float*)d_in[13];
  const float* bg     = (const float*)d_in[14];

  float* ws     = (float*)d_ws;
  float* xpcl   = ws;                          // 2097152 (dead after deform32)
  short* hcl    = (short*)ws;                  // overlays xpcl: 4194304 shorts
  float* y1     = ws + 2097152;                // 4194304
  float* y2     = ws + 6291456;                // 4194304
  float* part   = ws + 10485760;               // 131072
  float* stats1 = ws + 10616832;               // 128
  float* stats2 = ws + 10616960;               // 128
  short* wA     = (short*)(ws + 10617088);     // 294912
  short* wd1T   = wA + 294912;                 // 18432
  short* wd2T   = wd1T + 18432;                // 36864
  short* woT1   = wd2T + 36864;                // 9216
  short* woT2   = woT1 + 9216;                 // 18432

  (void)hipFuncSetAttribute((const void*)gates_mfma_k,
                            hipFuncAttributeMaxDynamicSharedMemorySize, 78848);

  maxpool_cl_k<<<dim3((BATCH*NP + 255)/256), dim3(256), 0, stream>>>(x, xpcl);
  wprep_all_k<<<dim3((377856 + 255)/256), dim3(256), 0, stream>>>(
      wg, w1, w2, w_off1, w_off2, wA, wd1T, wd2T, woT1, woT2);

  deform_fused_k<32,false><<<dim3(256, BATCH), dim3(256), 0, stream>>>(
      xpcl, stats1, b_off1, woT1, wd1T, y1, part);
  // xpcl dead from here; hcl overlay becomes writable
  h2cl_k<<<dim3(NP/64, BATCH), dim3(256), 0, stream>>>(h0, hcl);
  bnfinal2_k<<<dim3(64), dim3(256), 0, stream>>>(part, g1, be1, stats1);

  deform_fused_k<64,true><<<dim3(256, BATCH), dim3(256), 0, stream>>>(
      y1, stats1, b_off2, woT2, wd2T, y2, part);
  bnfinal2_k<<<dim3(64), dim3(256), 0, stream>>>(part, g2, be2, stats2);

  float* outh = (float*)d_out;
  float* outc = outh + (size_t)BATCH*64*NP;
  gates_mfma_k<<<dim3(128, BATCH), dim3(512), 78848, stream>>>(
      y2, stats2, hcl, c0, wA, bg, outh, outc);
}

// Round 13
// 123.989 us; speedup vs baseline: 1.1055x; 1.0606x over previous
//
#include <hip/hip_runtime.h>
#include <hip/hip_fp16.h>
#include <math.h>

#define P 128
#define NP (P*P)
#define BATCH 4

typedef __attribute__((ext_vector_type(8))) short bf16x8;
typedef __attribute__((ext_vector_type(8))) _Float16 h16x8;
typedef __attribute__((ext_vector_type(4))) float f32x4;

__device__ __forceinline__ float sigmoidf_(float x){ return 1.f/(1.f+__expf(-x)); }
__device__ __forceinline__ float tanhf_(float x){
  float ax = fabsf(x);
  float e = __expf(2.f*ax);
  float t = 1.f - 2.f/(e + 1.f);
  return copysignf(t, x);
}
__device__ __forceinline__ short f2bf(float f){
  unsigned u = __builtin_bit_cast(unsigned, f);
  u = (u + 0x7FFFu + ((u>>16)&1u)) >> 16;
  return (short)u;
}
__device__ __forceinline__ short f2h(float f){
  return (short)__half_as_short(__float2half(f));
}

// ---------------- maxpool 2x2 stride 2: (B,32,256,256) planar -> (B,P,P,32) channels-last ----------------
__global__ void maxpool_cl_k(const float* __restrict__ x, float* __restrict__ xp){
  int idx = blockIdx.x*256 + threadIdx.x;
  if (idx >= BATCH*NP) return;
  int wp = idx & (P-1); int t = idx >> 7; int hp = t & (P-1); int b = t >> 7;
  const float* src = x + ((size_t)b*32*65536) + (size_t)(hp*2)*256 + wp*2;
  float m[32];
  #pragma unroll
  for (int c = 0; c < 32; c++){
    const float* s = src + (size_t)c*65536;
    m[c] = fmaxf(fmaxf(s[0], s[1]), fmaxf(s[256], s[257]));
  }
  float* dst = xp + (size_t)idx*32;
  #pragma unroll
  for (int q = 0; q < 8; q++) *(float4*)(dst + q*4) = *(float4*)(m + q*4);
}

// ---------------- weight prep ----------------
// gates (bf16): [tap9][cb4][mb16][lane64][s8] — chunk (tap,cb) contiguous 16KB.
// deform/offconv tables: same layouts but fp16.
__global__ void wprep_all_k(const float* __restrict__ wg, const float* __restrict__ w1,
                            const float* __restrict__ w2, const float* __restrict__ wo1,
                            const float* __restrict__ wo2,
                            short* __restrict__ wA, short* __restrict__ wd1T,
                            short* __restrict__ wd2T, short* __restrict__ woT1,
                            short* __restrict__ woT2){
  int idx = blockIdx.x*256 + threadIdx.x;
  if (idx < 294912){
    int s = idx & 7; int l = (idx>>3) & 63; int mb = (idx>>9) & 15;
    int cb = (idx>>13) & 3; int tap = idx >> 15;
    int ln = l & 15, kg = l >> 4;
    int r = mb*16 + ln; int ch = r >> 2, gate = r & 3;
    int cin = cb*32 + kg*8 + s;
    wA[idx] = f2bf(wg[((size_t)(gate*64 + ch)*128 + cin)*9 + tap]);
    return;
  }
  idx -= 294912;
  if (idx < 18432){
    int s = idx & 7; int l = (idx>>3) & 63; int mb = (idx>>9) & 3; int tap = idx >> 11;
    int ln = l & 15, kg = l >> 4;
    int o = mb*16 + ln; int cin = kg*8 + s;
    wd1T[idx] = f2h(w1[((size_t)(o*32 + cin))*9 + tap]);
    return;
  }
  idx -= 18432;
  if (idx < 36864){
    int s = idx & 7; int l = (idx>>3) & 63; int mb = (idx>>9) & 3;
    int cb = (idx>>11) & 1; int tap = idx >> 12;
    int ln = l & 15, kg = l >> 4;
    int o = mb*16 + ln; int cin = cb*32 + kg*8 + s;
    wd2T[idx] = f2h(w2[((size_t)(o*64 + cin))*9 + tap]);
    return;
  }
  idx -= 36864;
  if (idx < 9216){
    int s = idx & 7; int l = (idx>>3) & 63; int mb = (idx>>9) & 1; int tap = idx >> 10;
    int ln = l & 15, kg = l >> 4;
    int o = mb*16 + ln; int cin = kg*8 + s;
    woT1[idx] = (o < 18) ? f2h(wo1[((size_t)(o*32 + cin))*9 + tap]) : (short)0;
    return;
  }
  idx -= 9216;
  if (idx < 18432){
    int s = idx & 7; int l = (idx>>3) & 63; int mb = (idx>>9) & 1;
    int cb = (idx>>10) & 1; int tap = idx >> 11;
    int ln = l & 15, kg = l >> 4;
    int o = mb*16 + ln; int cin = cb*32 + kg*8 + s;
    woT2[idx] = (o < 18) ? f2h(wo2[((size_t)(o*64 + cin))*9 + tap]) : (short)0;
  }
}

// ---------------- fused offset-conv + deformable conv (fp16 MFMA) + BN partial sums ----------------
template<int CIN, bool BNIN>
__global__ __launch_bounds__(256) void deform_fused_k(
    const float* __restrict__ incl, const float* __restrict__ bstats,
    const float* __restrict__ b_off,
    const short* __restrict__ woT, const short* __restrict__ wdT,
    float* __restrict__ outcl, float* __restrict__ part){
  const int HS = 14, NHP = HS*HS;
  const int ROWB = CIN*2;
  const int CG = CIN/8, CGS = (CIN==64)?3:2;
  const int PM = (CIN==64)?7:3;
  const int NCB = CIN/32;
  __shared__ short xt[NHP*CIN];
  __shared__ float off_lds[64][20];
  __shared__ float red_s[4][64], red_q[4][64];
  int tid = threadIdx.x;
  int tile = blockIdx.x, b = blockIdx.y;
  int tx0 = (tile & 15)*8, ty0 = (tile >> 4)*8;
  const float* inb = incl + (size_t)b*NP*CIN;
  // ---- stage halo fp32 -> fp16 (pk cvt), cg-fastest coalesced
  for (int e = tid; e < NHP*CG; e += 256){
    int cg = e & (CG-1), p = e >> CGS;
    int hr = p/HS, wc = p - hr*HS;
    int gy = ty0 + hr - 3, gx = tx0 + wc - 3;
    union { short s[8]; __half2 h[4]; h16x8 v; } u;
    if (((unsigned)gy < P) && ((unsigned)gx < P)){
      const float* src = inb + ((size_t)gy*P + gx)*CIN + cg*8;
      float4 a = *(const float4*)src, bb = *(const float4*)(src+4);
      if (BNIN){
        int c = cg*8;
        a.x = fmaxf(a.x*bstats[c+0]+bstats[64+c+0], 0.f);
        a.y = fmaxf(a.y*bstats[c+1]+bstats[64+c+1], 0.f);
        a.z = fmaxf(a.z*bstats[c+2]+bstats[64+c+2], 0.f);
        a.w = fmaxf(a.w*bstats[c+3]+bstats[64+c+3], 0.f);
        bb.x = fmaxf(bb.x*bstats[c+4]+bstats[64+c+4], 0.f);
        bb.y = fmaxf(bb.y*bstats[c+5]+bstats[64+c+5], 0.f);
        bb.z = fmaxf(bb.z*bstats[c+6]+bstats[64+c+6], 0.f);
        bb.w = fmaxf(bb.w*bstats[c+7]+bstats[64+c+7], 0.f);
      }
      u.h[0] = __float22half2_rn(float2{a.x, a.y});
      u.h[1] = __float22half2_rn(float2{a.z, a.w});
      u.h[2] = __float22half2_rn(float2{bb.x, bb.y});
      u.h[3] = __float22half2_rn(float2{bb.z, bb.w});
    } else {
      #pragma unroll
      for (int j = 0; j < 8; j++) u.s[j] = 0;
    }
    *(h16x8*)((char*)xt + p*ROWB + ((cg*16) ^ ((p & PM)<<4))) = u.v;
  }
  __syncthreads();

  int lane = tid & 63, wid = tid >> 6;
  int kg = lane >> 4, ln = lane & 15;
  int py = ty0 + wid*2 + (ln>>3), pxg = tx0 + (ln&7);
  int pl = wid*16 + ln;

  // ---- phase 2: offset conv (fp16 MFMA)
  {
    f32x4 acc_o[2];
    acc_o[0] = (f32x4){0.f,0.f,0.f,0.f};
    acc_o[1] = (f32x4){0.f,0.f,0.f,0.f};
    #pragma unroll
    for (int tap = 0; tap < 9; tap++){
      int ky = tap/3, kx = tap - (tap/3)*3;
      int lr = wid*2 + (ln>>3) + ky + 2;
      int lc = (ln&7) + kx + 2;
      int p = lr*HS + lc;
      #pragma unroll
      for (int cb = 0; cb < NCB; cb++){
        h16x8 bfv = *(const h16x8*)((const char*)xt + p*ROWB + (((cb*64) + kg*16) ^ ((p & PM)<<4)));
        h16x8 af0 = *(const h16x8*)(const void*)(woT + ((size_t)((tap*NCB + cb)*2 + 0)*512 + lane*8));
        h16x8 af1 = *(const h16x8*)(const void*)(woT + ((size_t)((tap*NCB + cb)*2 + 1)*512 + lane*8));
        acc_o[0] = __builtin_amdgcn_mfma_f32_16x16x32_f16(af0, bfv, acc_o[0], 0, 0, 0);
        acc_o[1] = __builtin_amdgcn_mfma_f32_16x16x32_f16(af1, bfv, acc_o[1], 0, 0, 0);
      }
    }
    #pragma unroll
    for (int mf = 0; mf < 2; mf++){
      #pragma unroll
      for (int j = 0; j < 4; j++){
        int o = mf*16 + kg*4 + j;
        if (o < 18) off_lds[pl][o] = acc_o[mf][j] + b_off[o];
      }
    }
  }
  __syncthreads();

  // ---- phase 3: bilinear sample (packed hfma2) + fp16 MFMA
  f32x4 acc[4];
  #pragma unroll
  for (int mf = 0; mf < 4; mf++) acc[mf] = (f32x4){0.f,0.f,0.f,0.f};

  for (int tap = 0; tap < 9; tap++){
    float dy = off_lds[pl][tap], dx = off_lds[pl][9+tap];
    float ys = (float)(py + tap/3 - 1) + dy;
    float xs = (float)(pxg + tap%3 - 1) + dx;
    float y0f = floorf(ys), x0f = floorf(xs);
    float wy1 = ys - y0f, wx1 = xs - x0f;
    float wy0 = 1.f - wy1, wx0 = 1.f - wx1;
    int y0 = (int)y0f, x0 = (int)x0f;
    bool v0y = ((unsigned)y0 < P), v1y = ((unsigned)(y0+1) < P);
    bool v0x = ((unsigned)x0 < P), v1x = ((unsigned)(x0+1) < P);
    float w00 = (v0y && v0x) ? wy0*wx0 : 0.f;
    float w01 = (v0y && v1x) ? wy0*wx1 : 0.f;
    float w10 = (v1y && v0x) ? wy1*wx0 : 0.f;
    float w11 = (v1y && v1x) ? wy1*wx1 : 0.f;
    __half2 w00h = __float2half2_rn(w00);
    __half2 w01h = __float2half2_rn(w01);
    __half2 w10h = __float2half2_rn(w10);
    __half2 w11h = __float2half2_rn(w11);
    int ly0 = min(max(y0 - ty0 + 3, 0), HS-1);
    int ly1 = min(max(y0 + 1 - ty0 + 3, 0), HS-1);
    int lx0 = min(max(x0 - tx0 + 3, 0), HS-1);
    int lx1 = min(max(x0 + 1 - tx0 + 3, 0), HS-1);
    int p00 = ly0*HS + lx0, p01 = ly0*HS + lx1;
    int p10 = ly1*HS + lx0, p11 = ly1*HS + lx1;
    #pragma unroll
    for (int cb = 0; cb < NCB; cb++){
      int ko = (cb*32 + kg*8)*2;
      union { __half2 h[4]; h16x8 v; } c00, c01, c10, c11, bu;
      c00.v = *(const h16x8*)((const char*)xt + p00*ROWB + (ko ^ ((p00 & PM)<<4)));
      c01.v = *(const h16x8*)((const char*)xt + p01*ROWB + (ko ^ ((p01 & PM)<<4)));
      c10.v = *(const h16x8*)((const char*)xt + p10*ROWB + (ko ^ ((p10 & PM)<<4)));
      c11.v = *(const h16x8*)((const char*)xt + p11*ROWB + (ko ^ ((p11 & PM)<<4)));
      #pragma unroll
      for (int j = 0; j < 4; j++){
        bu.h[j] = __hfma2(c00.h[j], w00h,
                  __hfma2(c01.h[j], w01h,
                  __hfma2(c10.h[j], w10h,
                  __hmul2(c11.h[j], w11h))));
      }
      #pragma unroll
      for (int mf = 0; mf < 4; mf++){
        h16x8 af = *(const h16x8*)(const void*)(wdT + ((size_t)((tap*NCB + cb)*4 + mf)*512 + lane*8));
        acc[mf] = __builtin_amdgcn_mfma_f32_16x16x32_f16(af, bu.v, acc[mf], 0, 0, 0);
      }
    }
  }
  #pragma unroll
  for (int mf = 0; mf < 4; mf++){
    float* dst = outcl + ((size_t)b*NP + (size_t)py*P + pxg)*64 + mf*16 + kg*4;
    *(f32x4*)dst = acc[mf];
  }

  // ---- BN partial sums
  #pragma unroll
  for (int mf = 0; mf < 4; mf++){
    #pragma unroll
    for (int j = 0; j < 4; j++){
      float s = acc[mf][j], q = s*s;
      #pragma unroll
      for (int o = 1; o < 16; o <<= 1){
        s += __shfl_xor(s, o);
        q += __shfl_xor(q, o);
      }
      if (ln == 0){
        int ch = mf*16 + kg*4 + j;
        red_s[wid][ch] = s;
        red_q[wid][ch] = q;
      }
    }
  }
  __syncthreads();
  int blk = b*256 + tile;
  if (tid < 128){
    int ch = tid & 63;
    float v = (tid < 64)
      ? (red_s[0][ch]+red_s[1][ch]+red_s[2][ch]+red_s[3][ch])
      : (red_q[0][ch]+red_q[1][ch]+red_q[2][ch]+red_q[3][ch]);
    part[(size_t)tid*1024 + blk] = v;
  }
}

// ---------------- BN finalize ----------------
__global__ void bnfinal2_k(const float* __restrict__ part, const float* __restrict__ g,
                           const float* __restrict__ be, float* __restrict__ stats){
  int ch = blockIdx.x;
  int tid = threadIdx.x;
  float S = 0.f, Q = 0.f;
  for (int i = tid; i < 1024; i += 256){
    S += part[(size_t)ch*1024 + i];
    Q += part[(size_t)(64+ch)*1024 + i];
  }
  __shared__ float rs[256], rq[256];
  rs[tid] = S; rq[tid] = Q;
  __syncthreads();
  for (int o = 128; o > 0; o >>= 1){
    if (tid < o){ rs[tid] += rs[tid+o]; rq[tid] += rq[tid+o]; }
    __syncthreads();
  }
  if (tid == 0){
    const float inv = 1.f/(float)(BATCH*NP);
    float mean = rs[0]*inv;
    float var = rq[0]*inv - mean*mean;
    float scale = rsqrtf(var + 1e-5f)*g[ch];
    stats[ch] = scale;
    stats[64+ch] = be[ch] - mean*scale;
  }
}

// h0 planar -> hcl channels-last bf16 (B,NP,64)
__global__ void h2cl_k(const float* __restrict__ h0, short* __restrict__ hcl){
  __shared__ float t[64][65];
  int b = blockIdx.y;
  int p0 = blockIdx.x*64;
  int pl = threadIdx.x & 63;
  int cq = threadIdx.x >> 6;
  const float* src = h0 + (size_t)b*64*NP + p0 + pl;
  #pragma unroll
  for (int i = 0; i < 16; i++)
    t[cq*16+i][pl] = src[(size_t)(cq*16+i)*NP];
  __syncthreads();
  int p = threadIdx.x >> 2, q = threadIdx.x & 3;
  short* dst = hcl + ((size_t)(b*NP + p0 + p))*64 + q*16;
  union { short s[8]; bf16x8 v; } o0, o1;
  #pragma unroll
  for (int i = 0; i < 8; i++){ o0.s[i] = f2bf(t[q*16+i][p]); o1.s[i] = f2bf(t[q*16+8+i][p]); }
  *(bf16x8*)dst = o0.v;
  *(bf16x8*)(dst+8) = o1.v;
}

// ---------------- gates conv (128->256) MFMA + fused BN2 + LSTM ----------------
// M=256/block, tile 16x8 px; 36 chunks of 16KB (tap,cb), double-buffered A with
// counted-vmcnt raw barriers. LDS 78.8KB -> 2 blocks/CU.
__global__ __launch_bounds__(512, 4) void gates_mfma_k(
    const float* __restrict__ y2, const float* __restrict__ stats,
    const short* __restrict__ hcl, const float* __restrict__ c0,
    const short* __restrict__ wA, const float* __restrict__ bg,
    float* __restrict__ outh, float* __restrict__ outc){
  extern __shared__ short lds[];
  short* bs = lds;                  // 180 px x 256B (swizzled) = 46080 B
  short* abuf = lds + 180*128;      // 2 x 8192 shorts (16 KB each)
  int tid = threadIdx.x;
  int tile = blockIdx.x, b = blockIdx.y;
  int tx0 = (tile & 7)*16, ty0 = (tile >> 3)*8;
  int lane = tid & 63, wid = tid >> 6;

  for (int e = tid; e < 180*16; e += 512){
    int cg = e & 15, p = e >> 4;
    int hr = p/18, wc = p - hr*18;
    int gy = ty0 + hr - 1, gx = tx0 + wc - 1;
    union { short s[8]; bf16x8 v; } u;
    if (((unsigned)gy < P) && ((unsigned)gx < P)){
      if (cg < 8){
        const float* src = y2 + ((size_t)(b*NP) + (size_t)gy*P + gx)*64 + cg*8;
        float4 a = *(const float4*)src, b4 = *(const float4*)(src+4);
        int c = cg*8;
        u.s[0] = f2bf(fmaxf(a.x*stats[c+0]+stats[64+c+0], 0.f));
        u.s[1] = f2bf(fmaxf(a.y*stats[c+1]+stats[64+c+1], 0.f));
        u.s[2] = f2bf(fmaxf(a.z*stats[c+2]+stats[64+c+2], 0.f));
        u.s[3] = f2bf(fmaxf(a.w*stats[c+3]+stats[64+c+3], 0.f));
        u.s[4] = f2bf(fmaxf(b4.x*stats[c+4]+stats[64+c+4], 0.f));
        u.s[5] = f2bf(fmaxf(b4.y*stats[c+5]+stats[64+c+5], 0.f));
        u.s[6] = f2bf(fmaxf(b4.z*stats[c+6]+stats[64+c+6], 0.f));
        u.s[7] = f2bf(fmaxf(b4.w*stats[c+7]+stats[64+c+7], 0.f));
      } else {
        u.v = *(const bf16x8*)(hcl + ((size_t)(b*NP) + (size_t)gy*P + gx)*64 + (cg-8)*8);
      }
    } else {
      #pragma unroll
      for (int j = 0; j < 8; j++) u.s[j] = 0;
    }
    *(bf16x8*)((char*)bs + p*256 + ((cg*16) ^ ((p&7)<<4))) = u.v;
  }

  auto stageA = [&](int c, int bi){
    const short* g = wA + (size_t)c*8192;
    short* l = abuf + bi*8192;
    #pragma unroll
    for (int i = 0; i < 2; i++){
      int unit = wid*2 + i;
      __builtin_amdgcn_global_load_lds(
          (const __attribute__((address_space(1))) unsigned int*)(g + (size_t)(unit*64 + lane)*8),
          (__attribute__((address_space(3))) unsigned int*)(l + (size_t)unit*512),
          16, 0, 0);
    }
  };

  stageA(0, 0);
  stageA(1, 1);
  __syncthreads();

  int kg = lane >> 4, ln = lane & 15;
  int ct = wid >> 1, nh = wid & 1;
  f32x4 acc[4][4];
  #pragma unroll
  for (int mf = 0; mf < 4; mf++)
    #pragma unroll
    for (int rr = 0; rr < 4; rr++) acc[mf][rr] = (f32x4){0.f,0.f,0.f,0.f};

  for (int c = 0; c < 36; c++){
    int cur = c & 1;
    int tap = c >> 2, cb = c & 3;
    int ky = tap/3, kx = tap - ky*3;
    const short* al = abuf + cur*8192;
    bf16x8 af[4], bf[4];
    #pragma unroll
    for (int mf = 0; mf < 4; mf++)
      af[mf] = *(const bf16x8*)(al + (size_t)(ct*4 + mf)*512 + lane*8);
    #pragma unroll
    for (int rr = 0; rr < 4; rr++){
      int p = (nh*4 + rr + ky)*18 + ln + kx;
      bf[rr] = *(const bf16x8*)((const char*)bs + p*256 + (((cb*64) + kg*16) ^ ((p&7)<<4)));
    }
    asm volatile("s_waitcnt lgkmcnt(0)" ::: "memory");
    __builtin_amdgcn_sched_barrier(0);
    __builtin_amdgcn_s_barrier();
    __builtin_amdgcn_sched_barrier(0);
    if (c + 2 < 36) stageA(c + 2, cur);
    #pragma unroll
    for (int rr = 0; rr < 4; rr++)
      #pragma unroll
      for (int mf = 0; mf < 4; mf++)
        acc[mf][rr] = __builtin_amdgcn_mfma_f32_16x16x32_bf16(af[mf], bf[rr], acc[mf][rr], 0, 0, 0);
    if (c + 2 < 36){
      asm volatile("s_waitcnt vmcnt(2)" ::: "memory");
    } else {
      asm volatile("s_waitcnt vmcnt(0)" ::: "memory");
    }
    __builtin_amdgcn_sched_barrier(0);
    __builtin_amdgcn_s_barrier();
    __builtin_amdgcn_sched_barrier(0);
  }

  #pragma unroll
  for (int mf = 0; mf < 4; mf++){
    int ch = ct*16 + mf*4 + kg;
    float bi = bg[ch], bff = bg[64+ch], bo = bg[128+ch], bgv = bg[192+ch];
    #pragma unroll
    for (int rr = 0; rr < 4; rr++){
      int py = ty0 + nh*4 + rr, px = tx0 + ln;
      size_t pidx = ((size_t)(b*64 + ch))*NP + (size_t)py*P + px;
      f32x4 a = acc[mf][rr];
      float cv = sigmoidf_(a[1]+bff)*c0[pidx] + sigmoidf_(a[0]+bi)*tanhf_(a[3]+bgv);
      float hv = sigmoidf_(a[2]+bo)*tanhf_(cv);
      outh[pidx] = hv;
      outc[pidx] = cv;
    }
  }
}

extern "C" void kernel_launch(void* const* d_in, const int* in_sizes, int n_in,
                              void* d_out, int out_size, void* d_ws, size_t ws_size,
                              hipStream_t stream) {
  const float* x      = (const float*)d_in[0];
  const float* h0     = (const float*)d_in[1];
  const float* c0     = (const float*)d_in[2];
  const float* w_off1 = (const float*)d_in[3];
  const float* b_off1 = (const float*)d_in[4];
  const float* w1     = (const float*)d_in[5];
  const float* g1     = (const float*)d_in[6];
  const float* be1    = (const float*)d_in[7];
  const float* w_off2 = (const float*)d_in[8];
  const float* b_off2 = (const float*)d_in[9];
  const float* w2     = (const float*)d_in[10];
  const float* g2     = (const float*)d_in[11];
  const float* be2    = (const float*)d_in[12];
  const float* wg     = (const float*)d_in[13];
  const float* bg     = (const float*)d_in[14];

  float* ws     = (float*)d_ws;
  float* xpcl   = ws;                          // 2097152 (dead after deform32)
  short* hcl    = (short*)ws;                  // overlays xpcl: 4194304 shorts
  float* y1     = ws + 2097152;                // 4194304
  float* y2     = ws + 6291456;                // 4194304
  float* part   = ws + 10485760;               // 131072
  float* stats1 = ws + 10616832;               // 128
  float* stats2 = ws + 10616960;               // 128
  short* wA     = (short*)(ws + 10617088);     // 294912
  short* wd1T   = wA + 294912;                 // 18432
  short* wd2T   = wd1T + 18432;                // 36864
  short* woT1   = wd2T + 36864;                // 9216
  short* woT2   = woT1 + 9216;                 // 18432

  (void)hipFuncSetAttribute((const void*)gates_mfma_k,
                            hipFuncAttributeMaxDynamicSharedMemorySize, 78848);

  maxpool_cl_k<<<dim3((BATCH*NP + 255)/256), dim3(256), 0, stream>>>(x, xpcl);
  wprep_all_k<<<dim3((377856 + 255)/256), dim3(256), 0, stream>>>(
      wg, w1, w2, w_off1, w_off2, wA, wd1T, wd2T, woT1, woT2);

  deform_fused_k<32,false><<<dim3(256, BATCH), dim3(256), 0, stream>>>(
      xpcl, stats1, b_off1, woT1, wd1T, y1, part);
  // xpcl dead from here; hcl overlay becomes writable
  h2cl_k<<<dim3(NP/64, BATCH), dim3(256), 0, stream>>>(h0, hcl);
  bnfinal2_k<<<dim3(64), dim3(256), 0, stream>>>(part, g1, be1, stats1);

  deform_fused_k<64,true><<<dim3(256, BATCH), dim3(256), 0, stream>>>(
      y1, stats1, b_off2, woT2, wd2T, y2, part);
  bnfinal2_k<<<dim3(64), dim3(256), 0, stream>>>(part, g2, be2, stats2);

  float* outh = (float*)d_out;
  float* outc = outh + (size_t)BATCH*64*NP;
  gates_mfma_k<<<dim3(128, BATCH), dim3(512), 78848, stream>>>(
      y2, stats2, hcl, c0, wA, bg, outh, outc);
}

// Round 14
// 123.496 us; speedup vs baseline: 1.1099x; 1.0040x over previous
//
#include <hip/hip_runtime.h>
#include <hip/hip_fp16.h>
#include <math.h>

#define P 128
#define NP (P*P)
#define BATCH 4

typedef __attribute__((ext_vector_type(8))) short bf16x8;
typedef __attribute__((ext_vector_type(8))) _Float16 h16x8;
typedef __attribute__((ext_vector_type(4))) float f32x4;

__device__ __forceinline__ float sigmoidf_(float x){ return 1.f/(1.f+__expf(-x)); }
__device__ __forceinline__ float tanhf_(float x){
  float ax = fabsf(x);
  float e = __expf(2.f*ax);
  float t = 1.f - 2.f/(e + 1.f);
  return copysignf(t, x);
}
__device__ __forceinline__ short f2bf(float f){
  unsigned u = __builtin_bit_cast(unsigned, f);
  u = (u + 0x7FFFu + ((u>>16)&1u)) >> 16;
  return (short)u;
}
__device__ __forceinline__ short f2h(float f){
  return (short)__half_as_short(__float2half(f));
}

// ---------------- merged: maxpool (256 blocks) + weight prep (1476 blocks) ----------------
// gates wA layout: [cb4][kx3][ky3][mb16][lane64][s8]; chunk c=(cb*3+kx)*3+ky contiguous 16KB.
__global__ void prep_k(const float* __restrict__ x, float* __restrict__ xp,
                       const float* __restrict__ wg, const float* __restrict__ w1,
                       const float* __restrict__ w2, const float* __restrict__ wo1,
                       const float* __restrict__ wo2,
                       short* __restrict__ wA, short* __restrict__ wd1T,
                       short* __restrict__ wd2T, short* __restrict__ woT1,
                       short* __restrict__ woT2){
  int bx = blockIdx.x;
  if (bx < 256){
    int idx = bx*256 + threadIdx.x;
    int wp = idx & (P-1); int t = idx >> 7; int hp = t & (P-1); int b = t >> 7;
    const float* src = x + ((size_t)b*32*65536) + (size_t)(hp*2)*256 + wp*2;
    float m[32];
    #pragma unroll
    for (int c = 0; c < 32; c++){
      const float* s = src + (size_t)c*65536;
      m[c] = fmaxf(fmaxf(s[0], s[1]), fmaxf(s[256], s[257]));
    }
    float* dst = xp + (size_t)idx*32;
    #pragma unroll
    for (int q = 0; q < 8; q++) *(float4*)(dst + q*4) = *(float4*)(m + q*4);
    return;
  }
  int idx = (bx - 256)*256 + threadIdx.x;
  if (idx < 294912){
    int s = idx & 7; int l = (idx>>3) & 63; int mb = (idx>>9) & 15;
    int t = idx >> 13;            // 0..35 = (cb*3+kx)*3+ky
    int ky = t % 3; int t2 = t / 3; int kx = t2 % 3; int cb = t2 / 3;
    int tap = ky*3 + kx;
    int ln = l & 15, kg = l >> 4;
    int r = mb*16 + ln; int ch = r >> 2, gate = r & 3;
    int cin = cb*32 + kg*8 + s;
    wA[idx] = f2bf(wg[((size_t)(gate*64 + ch)*128 + cin)*9 + tap]);
    return;
  }
  idx -= 294912;
  if (idx < 18432){
    int s = idx & 7; int l = (idx>>3) & 63; int mb = (idx>>9) & 3; int tap = idx >> 11;
    int ln = l & 15, kg = l >> 4;
    int o = mb*16 + ln; int cin = kg*8 + s;
    wd1T[idx] = f2h(w1[((size_t)(o*32 + cin))*9 + tap]);
    return;
  }
  idx -= 18432;
  if (idx < 36864){
    int s = idx & 7; int l = (idx>>3) & 63; int mb = (idx>>9) & 3;
    int cb = (idx>>11) & 1; int tap = idx >> 12;
    int ln = l & 15, kg = l >> 4;
    int o = mb*16 + ln; int cin = cb*32 + kg*8 + s;
    wd2T[idx] = f2h(w2[((size_t)(o*64 + cin))*9 + tap]);
    return;
  }
  idx -= 36864;
  if (idx < 9216){
    int s = idx & 7; int l = (idx>>3) & 63; int mb = (idx>>9) & 1; int tap = idx >> 10;
    int ln = l & 15, kg = l >> 4;
    int o = mb*16 + ln; int cin = kg*8 + s;
    woT1[idx] = (o < 18) ? f2h(wo1[((size_t)(o*32 + cin))*9 + tap]) : (short)0;
    return;
  }
  idx -= 9216;
  if (idx < 18432){
    int s = idx & 7; int l = (idx>>3) & 63; int mb = (idx>>9) & 1;
    int cb = (idx>>10) & 1; int tap = idx >> 11;
    int ln = l & 15, kg = l >> 4;
    int o = mb*16 + ln; int cin = cb*32 + kg*8 + s;
    woT2[idx] = (o < 18) ? f2h(wo2[((size_t)(o*64 + cin))*9 + tap]) : (short)0;
  }
}

// ---------------- fused offset-conv + deformable conv (fp16 MFMA) + BN partial sums ----------------
template<int CIN, bool BNIN>
__global__ __launch_bounds__(256) void deform_fused_k(
    const float* __restrict__ incl, const float* __restrict__ bstats,
    const float* __restrict__ b_off,
    const short* __restrict__ woT, const short* __restrict__ wdT,
    float* __restrict__ outcl, float* __restrict__ part){
  const int HS = 14, NHP = HS*HS;
  const int ROWB = CIN*2;
  const int CG = CIN/8, CGS = (CIN==64)?3:2;
  const int PM = (CIN==64)?7:3;
  const int NCB = CIN/32;
  __shared__ short xt[NHP*CIN];
  __shared__ float off_lds[64][20];
  __shared__ float red_s[4][64], red_q[4][64];
  int tid = threadIdx.x;
  int tile = blockIdx.x, b = blockIdx.y;
  int tx0 = (tile & 15)*8, ty0 = (tile >> 4)*8;
  const float* inb = incl + (size_t)b*NP*CIN;
  for (int e = tid; e < NHP*CG; e += 256){
    int cg = e & (CG-1), p = e >> CGS;
    int hr = p/HS, wc = p - hr*HS;
    int gy = ty0 + hr - 3, gx = tx0 + wc - 3;
    union { short s[8]; __half2 h[4]; h16x8 v; } u;
    if (((unsigned)gy < P) && ((unsigned)gx < P)){
      const float* src = inb + ((size_t)gy*P + gx)*CIN + cg*8;
      float4 a = *(const float4*)src, bb = *(const float4*)(src+4);
      if (BNIN){
        int c = cg*8;
        a.x = fmaxf(a.x*bstats[c+0]+bstats[64+c+0], 0.f);
        a.y = fmaxf(a.y*bstats[c+1]+bstats[64+c+1], 0.f);
        a.z = fmaxf(a.z*bstats[c+2]+bstats[64+c+2], 0.f);
        a.w = fmaxf(a.w*bstats[c+3]+bstats[64+c+3], 0.f);
        bb.x = fmaxf(bb.x*bstats[c+4]+bstats[64+c+4], 0.f);
        bb.y = fmaxf(bb.y*bstats[c+5]+bstats[64+c+5], 0.f);
        bb.z = fmaxf(bb.z*bstats[c+6]+bstats[64+c+6], 0.f);
        bb.w = fmaxf(bb.w*bstats[c+7]+bstats[64+c+7], 0.f);
      }
      u.h[0] = __float22half2_rn(float2{a.x, a.y});
      u.h[1] = __float22half2_rn(float2{a.z, a.w});
      u.h[2] = __float22half2_rn(float2{bb.x, bb.y});
      u.h[3] = __float22half2_rn(float2{bb.z, bb.w});
    } else {
      #pragma unroll
      for (int j = 0; j < 8; j++) u.s[j] = 0;
    }
    *(h16x8*)((char*)xt + p*ROWB + ((cg*16) ^ ((p & PM)<<4))) = u.v;
  }
  __syncthreads();

  int lane = tid & 63, wid = tid >> 6;
  int kg = lane >> 4, ln = lane & 15;
  int py = ty0 + wid*2 + (ln>>3), pxg = tx0 + (ln&7);
  int pl = wid*16 + ln;

  {
    f32x4 acc_o[2];
    acc_o[0] = (f32x4){0.f,0.f,0.f,0.f};
    acc_o[1] = (f32x4){0.f,0.f,0.f,0.f};
    #pragma unroll
    for (int tap = 0; tap < 9; tap++){
      int ky = tap/3, kx = tap - (tap/3)*3;
      int lr = wid*2 + (ln>>3) + ky + 2;
      int lc = (ln&7) + kx + 2;
      int p = lr*HS + lc;
      #pragma unroll
      for (int cb = 0; cb < NCB; cb++){
        h16x8 bfv = *(const h16x8*)((const char*)xt + p*ROWB + (((cb*64) + kg*16) ^ ((p & PM)<<4)));
        h16x8 af0 = *(const h16x8*)(const void*)(woT + ((size_t)((tap*NCB + cb)*2 + 0)*512 + lane*8));
        h16x8 af1 = *(const h16x8*)(const void*)(woT + ((size_t)((tap*NCB + cb)*2 + 1)*512 + lane*8));
        acc_o[0] = __builtin_amdgcn_mfma_f32_16x16x32_f16(af0, bfv, acc_o[0], 0, 0, 0);
        acc_o[1] = __builtin_amdgcn_mfma_f32_16x16x32_f16(af1, bfv, acc_o[1], 0, 0, 0);
      }
    }
    #pragma unroll
    for (int mf = 0; mf < 2; mf++){
      #pragma unroll
      for (int j = 0; j < 4; j++){
        int o = mf*16 + kg*4 + j;
        if (o < 18) off_lds[pl][o] = acc_o[mf][j] + b_off[o];
      }
    }
  }
  __syncthreads();

  f32x4 acc[4];
  #pragma unroll
  for (int mf = 0; mf < 4; mf++) acc[mf] = (f32x4){0.f,0.f,0.f,0.f};

  for (int tap = 0; tap < 9; tap++){
    float dy = off_lds[pl][tap], dx = off_lds[pl][9+tap];
    float ys = (float)(py + tap/3 - 1) + dy;
    float xs = (float)(pxg + tap%3 - 1) + dx;
    float y0f = floorf(ys), x0f = floorf(xs);
    float wy1 = ys - y0f, wx1 = xs - x0f;
    float wy0 = 1.f - wy1, wx0 = 1.f - wx1;
    int y0 = (int)y0f, x0 = (int)x0f;
    bool v0y = ((unsigned)y0 < P), v1y = ((unsigned)(y0+1) < P);
    bool v0x = ((unsigned)x0 < P), v1x = ((unsigned)(x0+1) < P);
    float w00 = (v0y && v0x) ? wy0*wx0 : 0.f;
    float w01 = (v0y && v1x) ? wy0*wx1 : 0.f;
    float w10 = (v1y && v0x) ? wy1*wx0 : 0.f;
    float w11 = (v1y && v1x) ? wy1*wx1 : 0.f;
    __half2 w00h = __float2half2_rn(w00);
    __half2 w01h = __float2half2_rn(w01);
    __half2 w10h = __float2half2_rn(w10);
    __half2 w11h = __float2half2_rn(w11);
    int ly0 = min(max(y0 - ty0 + 3, 0), HS-1);
    int ly1 = min(max(y0 + 1 - ty0 + 3, 0), HS-1);
    int lx0 = min(max(x0 - tx0 + 3, 0), HS-1);
    int lx1 = min(max(x0 + 1 - tx0 + 3, 0), HS-1);
    int p00 = ly0*HS + lx0, p01 = ly0*HS + lx1;
    int p10 = ly1*HS + lx0, p11 = ly1*HS + lx1;
    #pragma unroll
    for (int cb = 0; cb < NCB; cb++){
      int ko = (cb*32 + kg*8)*2;
      union { __half2 h[4]; h16x8 v; } c00, c01, c10, c11, bu;
      c00.v = *(const h16x8*)((const char*)xt + p00*ROWB + (ko ^ ((p00 & PM)<<4)));
      c01.v = *(const h16x8*)((const char*)xt + p01*ROWB + (ko ^ ((p01 & PM)<<4)));
      c10.v = *(const h16x8*)((const char*)xt + p10*ROWB + (ko ^ ((p10 & PM)<<4)));
      c11.v = *(const h16x8*)((const char*)xt + p11*ROWB + (ko ^ ((p11 & PM)<<4)));
      #pragma unroll
      for (int j = 0; j < 4; j++){
        bu.h[j] = __hfma2(c00.h[j], w00h,
                  __hfma2(c01.h[j], w01h,
                  __hfma2(c10.h[j], w10h,
                  __hmul2(c11.h[j], w11h))));
      }
      #pragma unroll
      for (int mf = 0; mf < 4; mf++){
        h16x8 af = *(const h16x8*)(const void*)(wdT + ((size_t)((tap*NCB + cb)*4 + mf)*512 + lane*8));
        acc[mf] = __builtin_amdgcn_mfma_f32_16x16x32_f16(af, bu.v, acc[mf], 0, 0, 0);
      }
    }
  }
  #pragma unroll
  for (int mf = 0; mf < 4; mf++){
    float* dst = outcl + ((size_t)b*NP + (size_t)py*P + pxg)*64 + mf*16 + kg*4;
    *(f32x4*)dst = acc[mf];
  }

  #pragma unroll
  for (int mf = 0; mf < 4; mf++){
    #pragma unroll
    for (int j = 0; j < 4; j++){
      float s = acc[mf][j], q = s*s;
      #pragma unroll
      for (int o = 1; o < 16; o <<= 1){
        s += __shfl_xor(s, o);
        q += __shfl_xor(q, o);
      }
      if (ln == 0){
        int ch = mf*16 + kg*4 + j;
        red_s[wid][ch] = s;
        red_q[wid][ch] = q;
      }
    }
  }
  __syncthreads();
  int blk = b*256 + tile;
  if (tid < 128){
    int ch = tid & 63;
    float v = (tid < 64)
      ? (red_s[0][ch]+red_s[1][ch]+red_s[2][ch]+red_s[3][ch])
      : (red_q[0][ch]+red_q[1][ch]+red_q[2][ch]+red_q[3][ch]);
    part[(size_t)tid*1024 + blk] = v;
  }
}

// ---------------- BN finalize (standalone, for stats2) ----------------
__global__ void bnfinal2_k(const float* __restrict__ part, const float* __restrict__ g,
                           const float* __restrict__ be, float* __restrict__ stats){
  int ch = blockIdx.x;
  int tid = threadIdx.x;
  float S = 0.f, Q = 0.f;
  for (int i = tid; i < 1024; i += 256){
    S += part[(size_t)ch*1024 + i];
    Q += part[(size_t)(64+ch)*1024 + i];
  }
  __shared__ float rs[256], rq[256];
  rs[tid] = S; rq[tid] = Q;
  __syncthreads();
  for (int o = 128; o > 0; o >>= 1){
    if (tid < o){ rs[tid] += rs[tid+o]; rq[tid] += rq[tid+o]; }
    __syncthreads();
  }
  if (tid == 0){
    const float inv = 1.f/(float)(BATCH*NP);
    float mean = rs[0]*inv;
    float var = rq[0]*inv - mean*mean;
    float scale = rsqrtf(var + 1e-5f)*g[ch];
    stats[ch] = scale;
    stats[64+ch] = be[ch] - mean*scale;
  }
}

// ---------------- merged: bnfinal2(stats1) [64 blocks] + h2cl [1024 blocks] ----------------
__global__ void aux1_k(const float* __restrict__ part, const float* __restrict__ g,
                       const float* __restrict__ be, float* __restrict__ stats,
                       const float* __restrict__ h0, short* __restrict__ hcl){
  int bx = blockIdx.x;
  int tid = threadIdx.x;
  if (bx < 64){
    int ch = bx;
    float S = 0.f, Q = 0.f;
    for (int i = tid; i < 1024; i += 256){
      S += part[(size_t)ch*1024 + i];
      Q += part[(size_t)(64+ch)*1024 + i];
    }
    __shared__ float rs[256], rq[256];
    rs[tid] = S; rq[tid] = Q;
    __syncthreads();
    for (int o = 128; o > 0; o >>= 1){
      if (tid < o){ rs[tid] += rs[tid+o]; rq[tid] += rq[tid+o]; }
      __syncthreads();
    }
    if (tid == 0){
      const float inv = 1.f/(float)(BATCH*NP);
      float mean = rs[0]*inv;
      float var = rq[0]*inv - mean*mean;
      float scale = rsqrtf(var + 1e-5f)*g[ch];
      stats[ch] = scale;
      stats[64+ch] = be[ch] - mean*scale;
    }
    return;
  }
  {
    __shared__ float t[64][65];
    int blk = bx - 64;
    int b = blk >> 8;
    int p0 = (blk & 255)*64;
    int pl = tid & 63;
    int cq = tid >> 6;
    const float* src = h0 + (size_t)b*64*NP + p0 + pl;
    #pragma unroll
    for (int i = 0; i < 16; i++)
      t[cq*16+i][pl] = src[(size_t)(cq*16+i)*NP];
    __syncthreads();
    int p = tid >> 2, q = tid & 3;
    short* dst = hcl + ((size_t)(b*NP + p0 + p))*64 + q*16;
    union { short s[8]; bf16x8 v; } o0, o1;
    #pragma unroll
    for (int i = 0; i < 8; i++){ o0.s[i] = f2bf(t[q*16+i][p]); o1.s[i] = f2bf(t[q*16+8+i][p]); }
    *(bf16x8*)dst = o0.v;
    *(bf16x8*)(dst+8) = o1.v;
  }
}

// ---------------- gates conv (128->256) MFMA + fused BN2 + LSTM ----------------
// (cb,kx,ky)-ordered chunks with ky-sliding 6-row B window: per chunk reads af[4] + (ky==0 ? 4 : 1) bf.
// 36 chunks of 16KB, double-buffered A, counted-vmcnt raw barriers. LDS 78.8KB -> 2 blocks/CU.
__global__ __launch_bounds__(512, 4) void gates_mfma_k(
    const float* __restrict__ y2, const float* __restrict__ stats,
    const short* __restrict__ hcl, const float* __restrict__ c0,
    const short* __restrict__ wA, const float* __restrict__ bg,
    float* __restrict__ outh, float* __restrict__ outc){
  extern __shared__ short lds[];
  short* bs = lds;                  // 180 px x 256B (swizzled) = 46080 B
  short* abuf = lds + 180*128;      // 2 x 8192 shorts (16 KB each)
  int tid = threadIdx.x;
  int tile = blockIdx.x, b = blockIdx.y;
  int tx0 = (tile & 7)*16, ty0 = (tile >> 3)*8;
  int lane = tid & 63, wid = tid >> 6;

  for (int e = tid; e < 180*16; e += 512){
    int cg = e & 15, p = e >> 4;
    int hr = p/18, wc = p - hr*18;
    int gy = ty0 + hr - 1, gx = tx0 + wc - 1;
    union { short s[8]; bf16x8 v; } u;
    if (((unsigned)gy < P) && ((unsigned)gx < P)){
      if (cg < 8){
        const float* src = y2 + ((size_t)(b*NP) + (size_t)gy*P + gx)*64 + cg*8;
        float4 a = *(const float4*)src, b4 = *(const float4*)(src+4);
        int c = cg*8;
        u.s[0] = f2bf(fmaxf(a.x*stats[c+0]+stats[64+c+0], 0.f));
        u.s[1] = f2bf(fmaxf(a.y*stats[c+1]+stats[64+c+1], 0.f));
        u.s[2] = f2bf(fmaxf(a.z*stats[c+2]+stats[64+c+2], 0.f));
        u.s[3] = f2bf(fmaxf(a.w*stats[c+3]+stats[64+c+3], 0.f));
        u.s[4] = f2bf(fmaxf(b4.x*stats[c+4]+stats[64+c+4], 0.f));
        u.s[5] = f2bf(fmaxf(b4.y*stats[c+5]+stats[64+c+5], 0.f));
        u.s[6] = f2bf(fmaxf(b4.z*stats[c+6]+stats[64+c+6], 0.f));
        u.s[7] = f2bf(fmaxf(b4.w*stats[c+7]+stats[64+c+7], 0.f));
      } else {
        u.v = *(const bf16x8*)(hcl + ((size_t)(b*NP) + (size_t)gy*P + gx)*64 + (cg-8)*8);
      }
    } else {
      #pragma unroll
      for (int j = 0; j < 8; j++) u.s[j] = 0;
    }
    *(bf16x8*)((char*)bs + p*256 + ((cg*16) ^ ((p&7)<<4))) = u.v;
  }

  auto stageA = [&](int c, int bi){
    const short* g = wA + (size_t)c*8192;
    short* l = abuf + bi*8192;
    #pragma unroll
    for (int i = 0; i < 2; i++){
      int unit = wid*2 + i;
      __builtin_amdgcn_global_load_lds(
          (const __attribute__((address_space(1))) unsigned int*)(g + (size_t)(unit*64 + lane)*8),
          (__attribute__((address_space(3))) unsigned int*)(l + (size_t)unit*512),
          16, 0, 0);
    }
  };

  stageA(0, 0);
  stageA(1, 1);
  __syncthreads();

  int kg = lane >> 4, ln = lane & 15;
  int ct = wid >> 1, nh = wid & 1;
  f32x4 acc[4][4];
  #pragma unroll
  for (int mf = 0; mf < 4; mf++)
    #pragma unroll
    for (int rr = 0; rr < 4; rr++) acc[mf][rr] = (f32x4){0.f,0.f,0.f,0.f};

  bf16x8 bwin[6];
  #pragma unroll
  for (int cb = 0; cb < 4; cb++){
    #pragma unroll
    for (int kx = 0; kx < 3; kx++){
      #pragma unroll
      for (int ky = 0; ky < 3; ky++){
        const int cc = (cb*3 + kx)*3 + ky;
        const short* al = abuf + (cc & 1)*8192;
        // B window reads: ky==0 -> rows 0..3; else 1 new row (ky+3)
        if (ky == 0){
          #pragma unroll
          for (int j = 0; j < 4; j++){
            int p = (nh*4 + j)*18 + ln + kx;
            bwin[j] = *(const bf16x8*)((const char*)bs + p*256 + (((cb*64) + kg*16) ^ ((p&7)<<4)));
          }
        } else {
          const int j = ky + 3;
          int p = (nh*4 + j)*18 + ln + kx;
          bwin[j] = *(const bf16x8*)((const char*)bs + p*256 + (((cb*64) + kg*16) ^ ((p&7)<<4)));
        }
        bf16x8 af[4];
        #pragma unroll
        for (int mf = 0; mf < 4; mf++)
          af[mf] = *(const bf16x8*)(al + (size_t)(ct*4 + mf)*512 + lane*8);
        // BARRIER A: all waves done reading abuf[cur]
        asm volatile("s_waitcnt lgkmcnt(0)" ::: "memory");
        __builtin_amdgcn_sched_barrier(0);
        __builtin_amdgcn_s_barrier();
        __builtin_amdgcn_sched_barrier(0);
        if (cc + 2 < 36) stageA(cc + 2, cc & 1);
        __builtin_amdgcn_s_setprio(1);
        #pragma unroll
        for (int rr = 0; rr < 4; rr++)
          #pragma unroll
          for (int mf = 0; mf < 4; mf++)
            acc[mf][rr] = __builtin_amdgcn_mfma_f32_16x16x32_bf16(af[mf], bwin[rr + ky], acc[mf][rr], 0, 0, 0);
        __builtin_amdgcn_s_setprio(0);
        // BARRIER B: chunk cc+1 landed (counted vmcnt keeps cc+2's 2 loads in flight)
        if (cc + 2 < 36){
          asm volatile("s_waitcnt vmcnt(2)" ::: "memory");
        } else {
          asm volatile("s_waitcnt vmcnt(0)" ::: "memory");
        }
        __builtin_amdgcn_sched_barrier(0);
        __builtin_amdgcn_s_barrier();
        __builtin_amdgcn_sched_barrier(0);
      }
    }
  }

  #pragma unroll
  for (int mf = 0; mf < 4; mf++){
    int ch = ct*16 + mf*4 + kg;
    float bi = bg[ch], bff = bg[64+ch], bo = bg[128+ch], bgv = bg[192+ch];
    #pragma unroll
    for (int rr = 0; rr < 4; rr++){
      int py = ty0 + nh*4 + rr, px = tx0 + ln;
      size_t pidx = ((size_t)(b*64 + ch))*NP + (size_t)py*P + px;
      f32x4 a = acc[mf][rr];
      float cv = sigmoidf_(a[1]+bff)*c0[pidx] + sigmoidf_(a[0]+bi)*tanhf_(a[3]+bgv);
      float hv = sigmoidf_(a[2]+bo)*tanhf_(cv);
      outh[pidx] = hv;
      outc[pidx] = cv;
    }
  }
}

extern "C" void kernel_launch(void* const* d_in, const int* in_sizes, int n_in,
                              void* d_out, int out_size, void* d_ws, size_t ws_size,
                              hipStream_t stream) {
  const float* x      = (const float*)d_in[0];
  const float* h0     = (const float*)d_in[1];
  const float* c0     = (const float*)d_in[2];
  const float* w_off1 = (const float*)d_in[3];
  const float* b_off1 = (const float*)d_in[4];
  const float* w1     = (const float*)d_in[5];
  const float* g1     = (const float*)d_in[6];
  const float* be1    = (const float*)d_in[7];
  const float* w_off2 = (const float*)d_in[8];
  const float* b_off2 = (const float*)d_in[9];
  const float* w2     = (const float*)d_in[10];
  const float* g2     = (const float*)d_in[11];
  const float* be2    = (const float*)d_in[12];
  const float* wg     = (const float*)d_in[13];
  const float* bg     = (const float*)d_in[14];

  float* ws     = (float*)d_ws;
  float* xpcl   = ws;                          // 2097152 (dead after deform32)
  short* hcl    = (short*)ws;                  // overlays xpcl: 4194304 shorts
  float* y1     = ws + 2097152;                // 4194304
  float* y2     = ws + 6291456;                // 4194304
  float* part   = ws + 10485760;               // 131072
  float* stats1 = ws + 10616832;               // 128
  float* stats2 = ws + 10616960;               // 128
  short* wA     = (short*)(ws + 10617088);     // 294912
  short* wd1T   = wA + 294912;                 // 18432
  short* wd2T   = wd1T + 18432;                // 36864
  short* woT1   = wd2T + 36864;                // 9216
  short* woT2   = woT1 + 9216;                 // 18432

  (void)hipFuncSetAttribute((const void*)gates_mfma_k,
                            hipFuncAttributeMaxDynamicSharedMemorySize, 78848);

  prep_k<<<dim3(256 + 1476), dim3(256), 0, stream>>>(
      x, xpcl, wg, w1, w2, w_off1, w_off2, wA, wd1T, wd2T, woT1, woT2);

  deform_fused_k<32,false><<<dim3(256, BATCH), dim3(256), 0, stream>>>(
      xpcl, stats1, b_off1, woT1, wd1T, y1, part);
  // xpcl dead from here; hcl overlay becomes writable
  aux1_k<<<dim3(64 + 1024), dim3(256), 0, stream>>>(part, g1, be1, stats1, h0, hcl);

  deform_fused_k<64,true><<<dim3(256, BATCH), dim3(256), 0, stream>>>(
      y1, stats1, b_off2, woT2, wd2T, y2, part);
  bnfinal2_k<<<dim3(64), dim3(256), 0, stream>>>(part, g2, be2, stats2);

  float* outh = (float*)d_out;
  float* outc = outh + (size_t)BATCH*64*NP;
  gates_mfma_k<<<dim3(128, BATCH), dim3(512), 78848, stream>>>(
      y2, stats2, hcl, c0, wA, bg, outh, outc);
}

// Round 15
// 118.858 us; speedup vs baseline: 1.1532x; 1.0390x over previous
//
#include <hip/hip_runtime.h>
#include <hip/hip_fp16.h>
#include <math.h>

#define P 128
#define NP (P*P)
#define BATCH 4

typedef __attribute__((ext_vector_type(8))) short bf16x8;
typedef __attribute__((ext_vector_type(8))) _Float16 h16x8;
typedef __attribute__((ext_vector_type(4))) float f32x4;

__device__ __forceinline__ float sigmoidf_(float x){ return 1.f/(1.f+__expf(-x)); }
__device__ __forceinline__ float tanhf_(float x){
  float ax = fabsf(x);
  float e = __expf(2.f*ax);
  float t = 1.f - 2.f/(e + 1.f);
  return copysignf(t, x);
}
__device__ __forceinline__ short f2bf(float f){
  unsigned u = __builtin_bit_cast(unsigned, f);
  u = (u + 0x7FFFu + ((u>>16)&1u)) >> 16;
  return (short)u;
}
__device__ __forceinline__ short f2h(float f){
  return (short)__half_as_short(__float2half(f));
}

// ---------------- merged: maxpool (256 blocks) + weight prep (1476 blocks) ----------------
// gates wA layout (round-13 proven): [tap9][cb4][mb16][lane64][s8]; chunk c=tap*4+cb contiguous 16KB.
__global__ void prep_k(const float* __restrict__ x, float* __restrict__ xp,
                       const float* __restrict__ wg, const float* __restrict__ w1,
                       const float* __restrict__ w2, const float* __restrict__ wo1,
                       const float* __restrict__ wo2,
                       short* __restrict__ wA, short* __restrict__ wd1T,
                       short* __restrict__ wd2T, short* __restrict__ woT1,
                       short* __restrict__ woT2){
  int bx = blockIdx.x;
  if (bx < 256){
    int idx = bx*256 + threadIdx.x;
    int wp = idx & (P-1); int t = idx >> 7; int hp = t & (P-1); int b = t >> 7;
    const float* src = x + ((size_t)b*32*65536) + (size_t)(hp*2)*256 + wp*2;
    float m[32];
    #pragma unroll
    for (int c = 0; c < 32; c++){
      const float* s = src + (size_t)c*65536;
      m[c] = fmaxf(fmaxf(s[0], s[1]), fmaxf(s[256], s[257]));
    }
    float* dst = xp + (size_t)idx*32;
    #pragma unroll
    for (int q = 0; q < 8; q++) *(float4*)(dst + q*4) = *(float4*)(m + q*4);
    return;
  }
  int idx = (bx - 256)*256 + threadIdx.x;
  if (idx < 294912){
    int s = idx & 7; int l = (idx>>3) & 63; int mb = (idx>>9) & 15;
    int cb = (idx>>13) & 3; int tap = idx >> 15;
    int ln = l & 15, kg = l >> 4;
    int r = mb*16 + ln; int ch = r >> 2, gate = r & 3;
    int cin = cb*32 + kg*8 + s;
    wA[idx] = f2bf(wg[((size_t)(gate*64 + ch)*128 + cin)*9 + tap]);
    return;
  }
  idx -= 294912;
  if (idx < 18432){
    int s = idx & 7; int l = (idx>>3) & 63; int mb = (idx>>9) & 3; int tap = idx >> 11;
    int ln = l & 15, kg = l >> 4;
    int o = mb*16 + ln; int cin = kg*8 + s;
    wd1T[idx] = f2h(w1[((size_t)(o*32 + cin))*9 + tap]);
    return;
  }
  idx -= 18432;
  if (idx < 36864){
    int s = idx & 7; int l = (idx>>3) & 63; int mb = (idx>>9) & 3;
    int cb = (idx>>11) & 1; int tap = idx >> 12;
    int ln = l & 15, kg = l >> 4;
    int o = mb*16 + ln; int cin = cb*32 + kg*8 + s;
    wd2T[idx] = f2h(w2[((size_t)(o*64 + cin))*9 + tap]);
    return;
  }
  idx -= 36864;
  if (idx < 9216){
    int s = idx & 7; int l = (idx>>3) & 63; int mb = (idx>>9) & 1; int tap = idx >> 10;
    int ln = l & 15, kg = l >> 4;
    int o = mb*16 + ln; int cin = kg*8 + s;
    woT1[idx] = (o < 18) ? f2h(wo1[((size_t)(o*32 + cin))*9 + tap]) : (short)0;
    return;
  }
  idx -= 9216;
  if (idx < 18432){
    int s = idx & 7; int l = (idx>>3) & 63; int mb = (idx>>9) & 1;
    int cb = (idx>>10) & 1; int tap = idx >> 11;
    int ln = l & 15, kg = l >> 4;
    int o = mb*16 + ln; int cin = cb*32 + kg*8 + s;
    woT2[idx] = (o < 18) ? f2h(wo2[((size_t)(o*64 + cin))*9 + tap]) : (short)0;
  }
}

// ---------------- fused offset-conv + deformable conv (fp16 MFMA) + BN partial sums ----------------
template<int CIN, bool BNIN>
__global__ __launch_bounds__(256) void deform_fused_k(
    const float* __restrict__ incl, const float* __restrict__ bstats,
    const float* __restrict__ b_off,
    const short* __restrict__ woT, const short* __restrict__ wdT,
    float* __restrict__ outcl, float* __restrict__ part){
  const int HS = 14, NHP = HS*HS;
  const int ROWB = CIN*2;
  const int CG = CIN/8, CGS = (CIN==64)?3:2;
  const int PM = (CIN==64)?7:3;
  const int NCB = CIN/32;
  __shared__ short xt[NHP*CIN];
  __shared__ float off_lds[64][20];
  __shared__ float red_s[4][64], red_q[4][64];
  int tid = threadIdx.x;
  int tile = blockIdx.x, b = blockIdx.y;
  int tx0 = (tile & 15)*8, ty0 = (tile >> 4)*8;
  const float* inb = incl + (size_t)b*NP*CIN;
  for (int e = tid; e < NHP*CG; e += 256){
    int cg = e & (CG-1), p = e >> CGS;
    int hr = p/HS, wc = p - hr*HS;
    int gy = ty0 + hr - 3, gx = tx0 + wc - 3;
    union { short s[8]; __half2 h[4]; h16x8 v; } u;
    if (((unsigned)gy < P) && ((unsigned)gx < P)){
      const float* src = inb + ((size_t)gy*P + gx)*CIN + cg*8;
      float4 a = *(const float4*)src, bb = *(const float4*)(src+4);
      if (BNIN){
        int c = cg*8;
        a.x = fmaxf(a.x*bstats[c+0]+bstats[64+c+0], 0.f);
        a.y = fmaxf(a.y*bstats[c+1]+bstats[64+c+1], 0.f);
        a.z = fmaxf(a.z*bstats[c+2]+bstats[64+c+2], 0.f);
        a.w = fmaxf(a.w*bstats[c+3]+bstats[64+c+3], 0.f);
        bb.x = fmaxf(bb.x*bstats[c+4]+bstats[64+c+4], 0.f);
        bb.y = fmaxf(bb.y*bstats[c+5]+bstats[64+c+5], 0.f);
        bb.z = fmaxf(bb.z*bstats[c+6]+bstats[64+c+6], 0.f);
        bb.w = fmaxf(bb.w*bstats[c+7]+bstats[64+c+7], 0.f);
      }
      u.h[0] = __float22half2_rn(float2{a.x, a.y});
      u.h[1] = __float22half2_rn(float2{a.z, a.w});
      u.h[2] = __float22half2_rn(float2{bb.x, bb.y});
      u.h[3] = __float22half2_rn(float2{bb.z, bb.w});
    } else {
      #pragma unroll
      for (int j = 0; j < 8; j++) u.s[j] = 0;
    }
    *(h16x8*)((char*)xt + p*ROWB + ((cg*16) ^ ((p & PM)<<4))) = u.v;
  }
  __syncthreads();

  int lane = tid & 63, wid = tid >> 6;
  int kg = lane >> 4, ln = lane & 15;
  int py = ty0 + wid*2 + (ln>>3), pxg = tx0 + (ln&7);
  int pl = wid*16 + ln;

  {
    f32x4 acc_o[2];
    acc_o[0] = (f32x4){0.f,0.f,0.f,0.f};
    acc_o[1] = (f32x4){0.f,0.f,0.f,0.f};
    #pragma unroll
    for (int tap = 0; tap < 9; tap++){
      int ky = tap/3, kx = tap - (tap/3)*3;
      int lr = wid*2 + (ln>>3) + ky + 2;
      int lc = (ln&7) + kx + 2;
      int p = lr*HS + lc;
      #pragma unroll
      for (int cb = 0; cb < NCB; cb++){
        h16x8 bfv = *(const h16x8*)((const char*)xt + p*ROWB + (((cb*64) + kg*16) ^ ((p & PM)<<4)));
        h16x8 af0 = *(const h16x8*)(const void*)(woT + ((size_t)((tap*NCB + cb)*2 + 0)*512 + lane*8));
        h16x8 af1 = *(const h16x8*)(const void*)(woT + ((size_t)((tap*NCB + cb)*2 + 1)*512 + lane*8));
        acc_o[0] = __builtin_amdgcn_mfma_f32_16x16x32_f16(af0, bfv, acc_o[0], 0, 0, 0);
        acc_o[1] = __builtin_amdgcn_mfma_f32_16x16x32_f16(af1, bfv, acc_o[1], 0, 0, 0);
      }
    }
    #pragma unroll
    for (int mf = 0; mf < 2; mf++){
      #pragma unroll
      for (int j = 0; j < 4; j++){
        int o = mf*16 + kg*4 + j;
        if (o < 18) off_lds[pl][o] = acc_o[mf][j] + b_off[o];
      }
    }
  }
  __syncthreads();

  f32x4 acc[4];
  #pragma unroll
  for (int mf = 0; mf < 4; mf++) acc[mf] = (f32x4){0.f,0.f,0.f,0.f};

  for (int tap = 0; tap < 9; tap++){
    float dy = off_lds[pl][tap], dx = off_lds[pl][9+tap];
    float ys = (float)(py + tap/3 - 1) + dy;
    float xs = (float)(pxg + tap%3 - 1) + dx;
    float y0f = floorf(ys), x0f = floorf(xs);
    float wy1 = ys - y0f, wx1 = xs - x0f;
    float wy0 = 1.f - wy1, wx0 = 1.f - wx1;
    int y0 = (int)y0f, x0 = (int)x0f;
    bool v0y = ((unsigned)y0 < P), v1y = ((unsigned)(y0+1) < P);
    bool v0x = ((unsigned)x0 < P), v1x = ((unsigned)(x0+1) < P);
    float w00 = (v0y && v0x) ? wy0*wx0 : 0.f;
    float w01 = (v0y && v1x) ? wy0*wx1 : 0.f;
    float w10 = (v1y && v0x) ? wy1*wx0 : 0.f;
    float w11 = (v1y && v1x) ? wy1*wx1 : 0.f;
    __half2 w00h = __float2half2_rn(w00);
    __half2 w01h = __float2half2_rn(w01);
    __half2 w10h = __float2half2_rn(w10);
    __half2 w11h = __float2half2_rn(w11);
    int ly0 = min(max(y0 - ty0 + 3, 0), HS-1);
    int ly1 = min(max(y0 + 1 - ty0 + 3, 0), HS-1);
    int lx0 = min(max(x0 - tx0 + 3, 0), HS-1);
    int lx1 = min(max(x0 + 1 - tx0 + 3, 0), HS-1);
    int p00 = ly0*HS + lx0, p01 = ly0*HS + lx1;
    int p10 = ly1*HS + lx0, p11 = ly1*HS + lx1;
    #pragma unroll
    for (int cb = 0; cb < NCB; cb++){
      int ko = (cb*32 + kg*8)*2;
      union { __half2 h[4]; h16x8 v; } c00, c01, c10, c11, bu;
      c00.v = *(const h16x8*)((const char*)xt + p00*ROWB + (ko ^ ((p00 & PM)<<4)));
      c01.v = *(const h16x8*)((const char*)xt + p01*ROWB + (ko ^ ((p01 & PM)<<4)));
      c10.v = *(const h16x8*)((const char*)xt + p10*ROWB + (ko ^ ((p10 & PM)<<4)));
      c11.v = *(const h16x8*)((const char*)xt + p11*ROWB + (ko ^ ((p11 & PM)<<4)));
      #pragma unroll
      for (int j = 0; j < 4; j++){
        bu.h[j] = __hfma2(c00.h[j], w00h,
                  __hfma2(c01.h[j], w01h,
                  __hfma2(c10.h[j], w10h,
                  __hmul2(c11.h[j], w11h))));
      }
      #pragma unroll
      for (int mf = 0; mf < 4; mf++){
        h16x8 af = *(const h16x8*)(const void*)(wdT + ((size_t)((tap*NCB + cb)*4 + mf)*512 + lane*8));
        acc[mf] = __builtin_amdgcn_mfma_f32_16x16x32_f16(af, bu.v, acc[mf], 0, 0, 0);
      }
    }
  }
  #pragma unroll
  for (int mf = 0; mf < 4; mf++){
    float* dst = outcl + ((size_t)b*NP + (size_t)py*P + pxg)*64 + mf*16 + kg*4;
    *(f32x4*)dst = acc[mf];
  }

  #pragma unroll
  for (int mf = 0; mf < 4; mf++){
    #pragma unroll
    for (int j = 0; j < 4; j++){
      float s = acc[mf][j], q = s*s;
      #pragma unroll
      for (int o = 1; o < 16; o <<= 1){
        s += __shfl_xor(s, o);
        q += __shfl_xor(q, o);
      }
      if (ln == 0){
        int ch = mf*16 + kg*4 + j;
        red_s[wid][ch] = s;
        red_q[wid][ch] = q;
      }
    }
  }
  __syncthreads();
  int blk = b*256 + tile;
  if (tid < 128){
    int ch = tid & 63;
    float v = (tid < 64)
      ? (red_s[0][ch]+red_s[1][ch]+red_s[2][ch]+red_s[3][ch])
      : (red_q[0][ch]+red_q[1][ch]+red_q[2][ch]+red_q[3][ch]);
    part[(size_t)tid*1024 + blk] = v;
  }
}

// ---------------- BN finalize (standalone, for stats2) ----------------
__global__ void bnfinal2_k(const float* __restrict__ part, const float* __restrict__ g,
                           const float* __restrict__ be, float* __restrict__ stats){
  int ch = blockIdx.x;
  int tid = threadIdx.x;
  float S = 0.f, Q = 0.f;
  for (int i = tid; i < 1024; i += 256){
    S += part[(size_t)ch*1024 + i];
    Q += part[(size_t)(64+ch)*1024 + i];
  }
  __shared__ float rs[256], rq[256];
  rs[tid] = S; rq[tid] = Q;
  __syncthreads();
  for (int o = 128; o > 0; o >>= 1){
    if (tid < o){ rs[tid] += rs[tid+o]; rq[tid] += rq[tid+o]; }
    __syncthreads();
  }
  if (tid == 0){
    const float inv = 1.f/(float)(BATCH*NP);
    float mean = rs[0]*inv;
    float var = rq[0]*inv - mean*mean;
    float scale = rsqrtf(var + 1e-5f)*g[ch];
    stats[ch] = scale;
    stats[64+ch] = be[ch] - mean*scale;
  }
}

// ---------------- merged: bnfinal2(stats1) [64 blocks] + h2cl [1024 blocks] ----------------
__global__ void aux1_k(const float* __restrict__ part, const float* __restrict__ g,
                       const float* __restrict__ be, float* __restrict__ stats,
                       const float* __restrict__ h0, short* __restrict__ hcl){
  int bx = blockIdx.x;
  int tid = threadIdx.x;
  if (bx < 64){
    int ch = bx;
    float S = 0.f, Q = 0.f;
    for (int i = tid; i < 1024; i += 256){
      S += part[(size_t)ch*1024 + i];
      Q += part[(size_t)(64+ch)*1024 + i];
    }
    __shared__ float rs[256], rq[256];
    rs[tid] = S; rq[tid] = Q;
    __syncthreads();
    for (int o = 128; o > 0; o >>= 1){
      if (tid < o){ rs[tid] += rs[tid+o]; rq[tid] += rq[tid+o]; }
      __syncthreads();
    }
    if (tid == 0){
      const float inv = 1.f/(float)(BATCH*NP);
      float mean = rs[0]*inv;
      float var = rq[0]*inv - mean*mean;
      float scale = rsqrtf(var + 1e-5f)*g[ch];
      stats[ch] = scale;
      stats[64+ch] = be[ch] - mean*scale;
    }
    return;
  }
  {
    __shared__ float t[64][65];
    int blk = bx - 64;
    int b = blk >> 8;
    int p0 = (blk & 255)*64;
    int pl = tid & 63;
    int cq = tid >> 6;
    const float* src = h0 + (size_t)b*64*NP + p0 + pl;
    #pragma unroll
    for (int i = 0; i < 16; i++)
      t[cq*16+i][pl] = src[(size_t)(cq*16+i)*NP];
    __syncthreads();
    int p = tid >> 2, q = tid & 3;
    short* dst = hcl + ((size_t)(b*NP + p0 + p))*64 + q*16;
    union { short s[8]; bf16x8 v; } o0, o1;
    #pragma unroll
    for (int i = 0; i < 8; i++){ o0.s[i] = f2bf(t[q*16+i][p]); o1.s[i] = f2bf(t[q*16+8+i][p]); }
    *(bf16x8*)dst = o0.v;
    *(bf16x8*)(dst+8) = o1.v;
  }
}

// ---------------- gates conv (128->256) MFMA + fused BN2 + LSTM ----------------
// Round-13 proven structure: M=256/block, tile 16x8 px; 36 chunks of 16KB (tap,cb),
// double-buffered A, counted-vmcnt raw barriers, + T5 setprio. LDS 78.8KB -> 2 blocks/CU.
__global__ __launch_bounds__(512, 4) void gates_mfma_k(
    const float* __restrict__ y2, const float* __restrict__ stats,
    const short* __restrict__ hcl, const float* __restrict__ c0,
    const short* __restrict__ wA, const float* __restrict__ bg,
    float* __restrict__ outh, float* __restrict__ outc){
  extern __shared__ short lds[];
  short* bs = lds;                  // 180 px x 256B (swizzled) = 46080 B
  short* abuf = lds + 180*128;      // 2 x 8192 shorts (16 KB each)
  int tid = threadIdx.x;
  int tile = blockIdx.x, b = blockIdx.y;
  int tx0 = (tile & 7)*16, ty0 = (tile >> 3)*8;
  int lane = tid & 63, wid = tid >> 6;

  for (int e = tid; e < 180*16; e += 512){
    int cg = e & 15, p = e >> 4;
    int hr = p/18, wc = p - hr*18;
    int gy = ty0 + hr - 1, gx = tx0 + wc - 1;
    union { short s[8]; bf16x8 v; } u;
    if (((unsigned)gy < P) && ((unsigned)gx < P)){
      if (cg < 8){
        const float* src = y2 + ((size_t)(b*NP) + (size_t)gy*P + gx)*64 + cg*8;
        float4 a = *(const float4*)src, b4 = *(const float4*)(src+4);
        int c = cg*8;
        u.s[0] = f2bf(fmaxf(a.x*stats[c+0]+stats[64+c+0], 0.f));
        u.s[1] = f2bf(fmaxf(a.y*stats[c+1]+stats[64+c+1], 0.f));
        u.s[2] = f2bf(fmaxf(a.z*stats[c+2]+stats[64+c+2], 0.f));
        u.s[3] = f2bf(fmaxf(a.w*stats[c+3]+stats[64+c+3], 0.f));
        u.s[4] = f2bf(fmaxf(b4.x*stats[c+4]+stats[64+c+4], 0.f));
        u.s[5] = f2bf(fmaxf(b4.y*stats[c+5]+stats[64+c+5], 0.f));
        u.s[6] = f2bf(fmaxf(b4.z*stats[c+6]+stats[64+c+6], 0.f));
        u.s[7] = f2bf(fmaxf(b4.w*stats[c+7]+stats[64+c+7], 0.f));
      } else {
        u.v = *(const bf16x8*)(hcl + ((size_t)(b*NP) + (size_t)gy*P + gx)*64 + (cg-8)*8);
      }
    } else {
      #pragma unroll
      for (int j = 0; j < 8; j++) u.s[j] = 0;
    }
    *(bf16x8*)((char*)bs + p*256 + ((cg*16) ^ ((p&7)<<4))) = u.v;
  }

  auto stageA = [&](int c, int bi){
    const short* g = wA + (size_t)c*8192;
    short* l = abuf + bi*8192;
    #pragma unroll
    for (int i = 0; i < 2; i++){
      int unit = wid*2 + i;
      __builtin_amdgcn_global_load_lds(
          (const __attribute__((address_space(1))) unsigned int*)(g + (size_t)(unit*64 + lane)*8),
          (__attribute__((address_space(3))) unsigned int*)(l + (size_t)unit*512),
          16, 0, 0);
    }
  };

  stageA(0, 0);
  stageA(1, 1);
  __syncthreads();

  int kg = lane >> 4, ln = lane & 15;
  int ct = wid >> 1, nh = wid & 1;
  f32x4 acc[4][4];
  #pragma unroll
  for (int mf = 0; mf < 4; mf++)
    #pragma unroll
    for (int rr = 0; rr < 4; rr++) acc[mf][rr] = (f32x4){0.f,0.f,0.f,0.f};

  for (int c = 0; c < 36; c++){
    int cur = c & 1;
    int tap = c >> 2, cb = c & 3;
    int ky = tap/3, kx = tap - ky*3;
    const short* al = abuf + cur*8192;
    bf16x8 af[4], bf[4];
    #pragma unroll
    for (int mf = 0; mf < 4; mf++)
      af[mf] = *(const bf16x8*)(al + (size_t)(ct*4 + mf)*512 + lane*8);
    #pragma unroll
    for (int rr = 0; rr < 4; rr++){
      int p = (nh*4 + rr + ky)*18 + ln + kx;
      bf[rr] = *(const bf16x8*)((const char*)bs + p*256 + (((cb*64) + kg*16) ^ ((p&7)<<4)));
    }
    asm volatile("s_waitcnt lgkmcnt(0)" ::: "memory");
    __builtin_amdgcn_sched_barrier(0);
    __builtin_amdgcn_s_barrier();
    __builtin_amdgcn_sched_barrier(0);
    if (c + 2 < 36) stageA(c + 2, cur);
    __builtin_amdgcn_s_setprio(1);
    #pragma unroll
    for (int rr = 0; rr < 4; rr++)
      #pragma unroll
      for (int mf = 0; mf < 4; mf++)
        acc[mf][rr] = __builtin_amdgcn_mfma_f32_16x16x32_bf16(af[mf], bf[rr], acc[mf][rr], 0, 0, 0);
    __builtin_amdgcn_s_setprio(0);
    if (c + 2 < 36){
      asm volatile("s_waitcnt vmcnt(2)" ::: "memory");
    } else {
      asm volatile("s_waitcnt vmcnt(0)" ::: "memory");
    }
    __builtin_amdgcn_sched_barrier(0);
    __builtin_amdgcn_s_barrier();
    __builtin_amdgcn_sched_barrier(0);
  }

  #pragma unroll
  for (int mf = 0; mf < 4; mf++){
    int ch = ct*16 + mf*4 + kg;
    float bi = bg[ch], bff = bg[64+ch], bo = bg[128+ch], bgv = bg[192+ch];
    #pragma unroll
    for (int rr = 0; rr < 4; rr++){
      int py = ty0 + nh*4 + rr, px = tx0 + ln;
      size_t pidx = ((size_t)(b*64 + ch))*NP + (size_t)py*P + px;
      f32x4 a = acc[mf][rr];
      float cv = sigmoidf_(a[1]+bff)*c0[pidx] + sigmoidf_(a[0]+bi)*tanhf_(a[3]+bgv);
      float hv = sigmoidf_(a[2]+bo)*tanhf_(cv);
      outh[pidx] = hv;
      outc[pidx] = cv;
    }
  }
}

extern "C" void kernel_launch(void* const* d_in, const int* in_sizes, int n_in,
                              void* d_out, int out_size, void* d_ws, size_t ws_size,
                              hipStream_t stream) {
  const float* x      = (const float*)d_in[0];
  const float* h0     = (const float*)d_in[1];
  const float* c0     = (const float*)d_in[2];
  const float* w_off1 = (const float*)d_in[3];
  const float* b_off1 = (const float*)d_in[4];
  const float* w1     = (const float*)d_in[5];
  const float* g1     = (const float*)d_in[6];
  const float* be1    = (const float*)d_in[7];
  const float* w_off2 = (const float*)d_in[8];
  const float* b_off2 = (const float*)d_in[9];
  const float* w2     = (const float*)d_in[10];
  const float* g2     = (const float*)d_in[11];
  const float* be2    = (const float*)d_in[12];
  const float* wg     = (const float*)d_in[13];
  const float* bg     = (const float*)d_in[14];

  float* ws     = (float*)d_ws;
  float* xpcl   = ws;                          // 2097152 (dead after deform32)
  short* hcl    = (short*)ws;                  // overlays xpcl: 4194304 shorts
  float* y1     = ws + 2097152;                // 4194304
  float* y2     = ws + 6291456;                // 4194304
  float* part   = ws + 10485760;               // 131072
  float* stats1 = ws + 10616832;               // 128
  float* stats2 = ws + 10616960;               // 128
  short* wA     = (short*)(ws + 10617088);     // 294912
  short* wd1T   = wA + 294912;                 // 18432
  short* wd2T   = wd1T + 18432;                // 36864
  short* woT1   = wd2T + 36864;                // 9216
  short* woT2   = woT1 + 9216;                 // 18432

  (void)hipFuncSetAttribute((const void*)gates_mfma_k,
                            hipFuncAttributeMaxDynamicSharedMemorySize, 78848);

  prep_k<<<dim3(256 + 1476), dim3(256), 0, stream>>>(
      x, xpcl, wg, w1, w2, w_off1, w_off2, wA, wd1T, wd2T, woT1, woT2);

  deform_fused_k<32,false><<<dim3(256, BATCH), dim3(256), 0, stream>>>(
      xpcl, stats1, b_off1, woT1, wd1T, y1, part);
  // xpcl dead from here; hcl overlay becomes writable
  aux1_k<<<dim3(64 + 1024), dim3(256), 0, stream>>>(part, g1, be1, stats1, h0, hcl);

  deform_fused_k<64,true><<<dim3(256, BATCH), dim3(256), 0, stream>>>(
      y1, stats1, b_off2, woT2, wd2T, y2, part);
  bnfinal2_k<<<dim3(64), dim3(256), 0, stream>>>(part, g2, be2, stats2);

  float* outh = (float*)d_out;
  float* outc = outh + (size_t)BATCH*64*NP;
  gates_mfma_k<<<dim3(128, BATCH), dim3(512), 78848, stream>>>(
      y2, stats2, hcl, c0, wA, bg, outh, outc);
}

// Round 16
// 117.991 us; speedup vs baseline: 1.1617x; 1.0073x over previous
//
#include <hip/hip_runtime.h>
#include <hip/hip_fp16.h>
#include <math.h>

#define P 128
#define NP (P*P)
#define BATCH 4

typedef __attribute__((ext_vector_type(8))) short bf16x8;
typedef __attribute__((ext_vector_type(8))) _Float16 h16x8;
typedef __attribute__((ext_vector_type(4))) float f32x4;

__device__ __forceinline__ float sigmoidf_(float x){ return 1.f/(1.f+__expf(-x)); }
__device__ __forceinline__ float tanhf_(float x){
  float ax = fabsf(x);
  float e = __expf(2.f*ax);
  float t = 1.f - 2.f/(e + 1.f);
  return copysignf(t, x);
}
__device__ __forceinline__ short f2bf(float f){
  unsigned u = __builtin_bit_cast(unsigned, f);
  u = (u + 0x7FFFu + ((u>>16)&1u)) >> 16;
  return (short)u;
}
__device__ __forceinline__ short f2h(float f){
  return (short)__half_as_short(__float2half(f));
}

// ---------------- merged: maxpool (256 blocks) + weight prep (1476 blocks) ----------------
// gates wA layout: [tap9][cb4][mb16][lane64][s8]; chunk c=tap*4+cb contiguous 16KB.
__global__ void prep_k(const float* __restrict__ x, float* __restrict__ xp,
                       const float* __restrict__ wg, const float* __restrict__ w1,
                       const float* __restrict__ w2, const float* __restrict__ wo1,
                       const float* __restrict__ wo2,
                       short* __restrict__ wA, short* __restrict__ wd1T,
                       short* __restrict__ wd2T, short* __restrict__ woT1,
                       short* __restrict__ woT2){
  int bx = blockIdx.x;
  if (bx < 256){
    int idx = bx*256 + threadIdx.x;
    int wp = idx & (P-1); int t = idx >> 7; int hp = t & (P-1); int b = t >> 7;
    const float* src = x + ((size_t)b*32*65536) + (size_t)(hp*2)*256 + wp*2;
    float m[32];
    #pragma unroll
    for (int c = 0; c < 32; c++){
      const float* s = src + (size_t)c*65536;
      float2 t0 = *(const float2*)s;
      float2 t1 = *(const float2*)(s + 256);
      m[c] = fmaxf(fmaxf(t0.x, t0.y), fmaxf(t1.x, t1.y));
    }
    float* dst = xp + (size_t)idx*32;
    #pragma unroll
    for (int q = 0; q < 8; q++) *(float4*)(dst + q*4) = *(float4*)(m + q*4);
    return;
  }
  int idx = (bx - 256)*256 + threadIdx.x;
  if (idx < 294912){
    int s = idx & 7; int l = (idx>>3) & 63; int mb = (idx>>9) & 15;
    int cb = (idx>>13) & 3; int tap = idx >> 15;
    int ln = l & 15, kg = l >> 4;
    int r = mb*16 + ln; int ch = r >> 2, gate = r & 3;
    int cin = cb*32 + kg*8 + s;
    wA[idx] = f2bf(wg[((size_t)(gate*64 + ch)*128 + cin)*9 + tap]);
    return;
  }
  idx -= 294912;
  if (idx < 18432){
    int s = idx & 7; int l = (idx>>3) & 63; int mb = (idx>>9) & 3; int tap = idx >> 11;
    int ln = l & 15, kg = l >> 4;
    int o = mb*16 + ln; int cin = kg*8 + s;
    wd1T[idx] = f2h(w1[((size_t)(o*32 + cin))*9 + tap]);
    return;
  }
  idx -= 18432;
  if (idx < 36864){
    int s = idx & 7; int l = (idx>>3) & 63; int mb = (idx>>9) & 3;
    int cb = (idx>>11) & 1; int tap = idx >> 12;
    int ln = l & 15, kg = l >> 4;
    int o = mb*16 + ln; int cin = cb*32 + kg*8 + s;
    wd2T[idx] = f2h(w2[((size_t)(o*64 + cin))*9 + tap]);
    return;
  }
  idx -= 36864;
  if (idx < 9216){
    int s = idx & 7; int l = (idx>>3) & 63; int mb = (idx>>9) & 1; int tap = idx >> 10;
    int ln = l & 15, kg = l >> 4;
    int o = mb*16 + ln; int cin = kg*8 + s;
    woT1[idx] = (o < 18) ? f2h(wo1[((size_t)(o*32 + cin))*9 + tap]) : (short)0;
    return;
  }
  idx -= 9216;
  if (idx < 18432){
    int s = idx & 7; int l = (idx>>3) & 63; int mb = (idx>>9) & 1;
    int cb = (idx>>10) & 1; int tap = idx >> 11;
    int ln = l & 15, kg = l >> 4;
    int o = mb*16 + ln; int cin = cb*32 + kg*8 + s;
    woT2[idx] = (o < 18) ? f2h(wo2[((size_t)(o*64 + cin))*9 + tap]) : (short)0;
  }
}

// ---------------- fused offset-conv + deformable conv (fp16 MFMA) + BN partial sums ----------------
template<int CIN, bool BNIN>
__global__ __launch_bounds__(256) void deform_fused_k(
    const float* __restrict__ incl, const float* __restrict__ bstats,
    const float* __restrict__ b_off,
    const short* __restrict__ woT, const short* __restrict__ wdT,
    float* __restrict__ outcl, float* __restrict__ part){
  const int HS = 14, NHP = HS*HS;
  const int ROWB = CIN*2;
  const int CG = CIN/8, CGS = (CIN==64)?3:2;
  const int PM = (CIN==64)?7:3;
  const int NCB = CIN/32;
  __shared__ short xt[NHP*CIN];
  __shared__ float off_lds[64][20];
  __shared__ float red_s[4][64], red_q[4][64];
  int tid = threadIdx.x;
  int tile = blockIdx.x, b = blockIdx.y;
  int tx0 = (tile & 15)*8, ty0 = (tile >> 4)*8;
  const float* inb = incl + (size_t)b*NP*CIN;
  for (int e = tid; e < NHP*CG; e += 256){
    int cg = e & (CG-1), p = e >> CGS;
    int hr = p/HS, wc = p - hr*HS;
    int gy = ty0 + hr - 3, gx = tx0 + wc - 3;
    union { short s[8]; __half2 h[4]; h16x8 v; } u;
    if (((unsigned)gy < P) && ((unsigned)gx < P)){
      const float* src = inb + ((size_t)gy*P + gx)*CIN + cg*8;
      float4 a = *(const float4*)src, bb = *(const float4*)(src+4);
      if (BNIN){
        int c = cg*8;
        a.x = fmaxf(a.x*bstats[c+0]+bstats[64+c+0], 0.f);
        a.y = fmaxf(a.y*bstats[c+1]+bstats[64+c+1], 0.f);
        a.z = fmaxf(a.z*bstats[c+2]+bstats[64+c+2], 0.f);
        a.w = fmaxf(a.w*bstats[c+3]+bstats[64+c+3], 0.f);
        bb.x = fmaxf(bb.x*bstats[c+4]+bstats[64+c+4], 0.f);
        bb.y = fmaxf(bb.y*bstats[c+5]+bstats[64+c+5], 0.f);
        bb.z = fmaxf(bb.z*bstats[c+6]+bstats[64+c+6], 0.f);
        bb.w = fmaxf(bb.w*bstats[c+7]+bstats[64+c+7], 0.f);
      }
      u.h[0] = __float22half2_rn(float2{a.x, a.y});
      u.h[1] = __float22half2_rn(float2{a.z, a.w});
      u.h[2] = __float22half2_rn(float2{bb.x, bb.y});
      u.h[3] = __float22half2_rn(float2{bb.z, bb.w});
    } else {
      #pragma unroll
      for (int j = 0; j < 8; j++) u.s[j] = 0;
    }
    *(h16x8*)((char*)xt + p*ROWB + ((cg*16) ^ ((p & PM)<<4))) = u.v;
  }
  __syncthreads();

  int lane = tid & 63, wid = tid >> 6;
  int kg = lane >> 4, ln = lane & 15;
  int py = ty0 + wid*2 + (ln>>3), pxg = tx0 + (ln&7);
  int pl = wid*16 + ln;

  {
    f32x4 acc_o[2];
    acc_o[0] = (f32x4){0.f,0.f,0.f,0.f};
    acc_o[1] = (f32x4){0.f,0.f,0.f,0.f};
    #pragma unroll
    for (int tap = 0; tap < 9; tap++){
      int ky = tap/3, kx = tap - (tap/3)*3;
      int lr = wid*2 + (ln>>3) + ky + 2;
      int lc = (ln&7) + kx + 2;
      int p = lr*HS + lc;
      #pragma unroll
      for (int cb = 0; cb < NCB; cb++){
        h16x8 bfv = *(const h16x8*)((const char*)xt + p*ROWB + (((cb*64) + kg*16) ^ ((p & PM)<<4)));
        h16x8 af0 = *(const h16x8*)(const void*)(woT + ((size_t)((tap*NCB + cb)*2 + 0)*512 + lane*8));
        h16x8 af1 = *(const h16x8*)(const void*)(woT + ((size_t)((tap*NCB + cb)*2 + 1)*512 + lane*8));
        acc_o[0] = __builtin_amdgcn_mfma_f32_16x16x32_f16(af0, bfv, acc_o[0], 0, 0, 0);
        acc_o[1] = __builtin_amdgcn_mfma_f32_16x16x32_f16(af1, bfv, acc_o[1], 0, 0, 0);
      }
    }
    #pragma unroll
    for (int mf = 0; mf < 2; mf++){
      #pragma unroll
      for (int j = 0; j < 4; j++){
        int o = mf*16 + kg*4 + j;
        if (o < 18) off_lds[pl][o] = acc_o[mf][j] + b_off[o];
      }
    }
  }
  __syncthreads();

  f32x4 acc[4];
  #pragma unroll
  for (int mf = 0; mf < 4; mf++) acc[mf] = (f32x4){0.f,0.f,0.f,0.f};

  for (int tap = 0; tap < 9; tap++){
    float dy = off_lds[pl][tap], dx = off_lds[pl][9+tap];
    float ys = (float)(py + tap/3 - 1) + dy;
    float xs = (float)(pxg + tap%3 - 1) + dx;
    float y0f = floorf(ys), x0f = floorf(xs);
    float wy1 = ys - y0f, wx1 = xs - x0f;
    float wy0 = 1.f - wy1, wx0 = 1.f - wx1;
    int y0 = (int)y0f, x0 = (int)x0f;
    bool v0y = ((unsigned)y0 < P), v1y = ((unsigned)(y0+1) < P);
    bool v0x = ((unsigned)x0 < P), v1x = ((unsigned)(x0+1) < P);
    float w00 = (v0y && v0x) ? wy0*wx0 : 0.f;
    float w01 = (v0y && v1x) ? wy0*wx1 : 0.f;
    float w10 = (v1y && v0x) ? wy1*wx0 : 0.f;
    float w11 = (v1y && v1x) ? wy1*wx1 : 0.f;
    __half2 w00h = __float2half2_rn(w00);
    __half2 w01h = __float2half2_rn(w01);
    __half2 w10h = __float2half2_rn(w10);
    __half2 w11h = __float2half2_rn(w11);
    int ly0 = min(max(y0 - ty0 + 3, 0), HS-1);
    int ly1 = min(max(y0 + 1 - ty0 + 3, 0), HS-1);
    int lx0 = min(max(x0 - tx0 + 3, 0), HS-1);
    int lx1 = min(max(x0 + 1 - tx0 + 3, 0), HS-1);
    int p00 = ly0*HS + lx0, p01 = ly0*HS + lx1;
    int p10 = ly1*HS + lx0, p11 = ly1*HS + lx1;
    #pragma unroll
    for (int cb = 0; cb < NCB; cb++){
      int ko = (cb*32 + kg*8)*2;
      union { __half2 h[4]; h16x8 v; } c00, c01, c10, c11, bu;
      c00.v = *(const h16x8*)((const char*)xt + p00*ROWB + (ko ^ ((p00 & PM)<<4)));
      c01.v = *(const h16x8*)((const char*)xt + p01*ROWB + (ko ^ ((p01 & PM)<<4)));
      c10.v = *(const h16x8*)((const char*)xt + p10*ROWB + (ko ^ ((p10 & PM)<<4)));
      c11.v = *(const h16x8*)((const char*)xt + p11*ROWB + (ko ^ ((p11 & PM)<<4)));
      #pragma unroll
      for (int j = 0; j < 4; j++){
        bu.h[j] = __hfma2(c00.h[j], w00h,
                  __hfma2(c01.h[j], w01h,
                  __hfma2(c10.h[j], w10h,
                  __hmul2(c11.h[j], w11h))));
      }
      #pragma unroll
      for (int mf = 0; mf < 4; mf++){
        h16x8 af = *(const h16x8*)(const void*)(wdT + ((size_t)((tap*NCB + cb)*4 + mf)*512 + lane*8));
        acc[mf] = __builtin_amdgcn_mfma_f32_16x16x32_f16(af, bu.v, acc[mf], 0, 0, 0);
      }
    }
  }
  #pragma unroll
  for (int mf = 0; mf < 4; mf++){
    float* dst = outcl + ((size_t)b*NP + (size_t)py*P + pxg)*64 + mf*16 + kg*4;
    *(f32x4*)dst = acc[mf];
  }

  #pragma unroll
  for (int mf = 0; mf < 4; mf++){
    #pragma unroll
    for (int j = 0; j < 4; j++){
      float s = acc[mf][j], q = s*s;
      #pragma unroll
      for (int o = 1; o < 16; o <<= 1){
        s += __shfl_xor(s, o);
        q += __shfl_xor(q, o);
      }
      if (ln == 0){
        int ch = mf*16 + kg*4 + j;
        red_s[wid][ch] = s;
        red_q[wid][ch] = q;
      }
    }
  }
  __syncthreads();
  int blk = b*256 + tile;
  if (tid < 128){
    int ch = tid & 63;
    float v = (tid < 64)
      ? (red_s[0][ch]+red_s[1][ch]+red_s[2][ch]+red_s[3][ch])
      : (red_q[0][ch]+red_q[1][ch]+red_q[2][ch]+red_q[3][ch]);
    part[(size_t)tid*1024 + blk] = v;
  }
}

// ---------------- BN finalize (standalone, for stats2) ----------------
__global__ void bnfinal2_k(const float* __restrict__ part, const float* __restrict__ g,
                           const float* __restrict__ be, float* __restrict__ stats){
  int ch = blockIdx.x;
  int tid = threadIdx.x;
  float S = 0.f, Q = 0.f;
  for (int i = tid; i < 1024; i += 256){
    S += part[(size_t)ch*1024 + i];
    Q += part[(size_t)(64+ch)*1024 + i];
  }
  __shared__ float rs[256], rq[256];
  rs[tid] = S; rq[tid] = Q;
  __syncthreads();
  for (int o = 128; o > 0; o >>= 1){
    if (tid < o){ rs[tid] += rs[tid+o]; rq[tid] += rq[tid+o]; }
    __syncthreads();
  }
  if (tid == 0){
    const float inv = 1.f/(float)(BATCH*NP);
    float mean = rs[0]*inv;
    float var = rq[0]*inv - mean*mean;
    float scale = rsqrtf(var + 1e-5f)*g[ch];
    stats[ch] = scale;
    stats[64+ch] = be[ch] - mean*scale;
  }
}

// ---------------- merged: bnfinal2(stats1) [64 blocks] + h2cl [1024 blocks] ----------------
__global__ void aux1_k(const float* __restrict__ part, const float* __restrict__ g,
                       const float* __restrict__ be, float* __restrict__ stats,
                       const float* __restrict__ h0, short* __restrict__ hcl){
  int bx = blockIdx.x;
  int tid = threadIdx.x;
  if (bx < 64){
    int ch = bx;
    float S = 0.f, Q = 0.f;
    for (int i = tid; i < 1024; i += 256){
      S += part[(size_t)ch*1024 + i];
      Q += part[(size_t)(64+ch)*1024 + i];
    }
    __shared__ float rs[256], rq[256];
    rs[tid] = S; rq[tid] = Q;
    __syncthreads();
    for (int o = 128; o > 0; o >>= 1){
      if (tid < o){ rs[tid] += rs[tid+o]; rq[tid] += rq[tid+o]; }
      __syncthreads();
    }
    if (tid == 0){
      const float inv = 1.f/(float)(BATCH*NP);
      float mean = rs[0]*inv;
      float var = rq[0]*inv - mean*mean;
      float scale = rsqrtf(var + 1e-5f)*g[ch];
      stats[ch] = scale;
      stats[64+ch] = be[ch] - mean*scale;
    }
    return;
  }
  {
    __shared__ float t[64][65];
    int blk = bx - 64;
    int b = blk >> 8;
    int p0 = (blk & 255)*64;
    int pl = tid & 63;
    int cq = tid >> 6;
    const float* src = h0 + (size_t)b*64*NP + p0 + pl;
    #pragma unroll
    for (int i = 0; i < 16; i++)
      t[cq*16+i][pl] = src[(size_t)(cq*16+i)*NP];
    __syncthreads();
    int p = tid >> 2, q = tid & 3;
    short* dst = hcl + ((size_t)(b*NP + p0 + p))*64 + q*16;
    union { short s[8]; bf16x8 v; } o0, o1;
    #pragma unroll
    for (int i = 0; i < 8; i++){ o0.s[i] = f2bf(t[q*16+i][p]); o1.s[i] = f2bf(t[q*16+8+i][p]); }
    *(bf16x8*)dst = o0.v;
    *(bf16x8*)(dst+8) = o1.v;
  }
}

// ---------------- gates conv (128->256) MFMA + fused BN2 + LSTM ----------------
// M=256/block, tile 16x8 px; 36 chunks of 16KB (tap,cb), double-buffered A.
// SINGLE barrier per chunk: {ds_read -> lgkm(0) -> MFMA -> vmcnt(0) -> barrier -> stage(c+2)}.
// Barrier proves both (a) all waves done reading cur and (b) all waves' stage(c+1) landed
// (each wave drains its own loads via vmcnt(0) pre-barrier). LDS 78.8KB -> 2 blocks/CU.
__global__ __launch_bounds__(512, 4) void gates_mfma_k(
    const float* __restrict__ y2, const float* __restrict__ stats,
    const short* __restrict__ hcl, const float* __restrict__ c0,
    const short* __restrict__ wA, const float* __restrict__ bg,
    float* __restrict__ outh, float* __restrict__ outc){
  extern __shared__ short lds[];
  short* bs = lds;                  // 180 px x 256B (swizzled) = 46080 B
  short* abuf = lds + 180*128;      // 2 x 8192 shorts (16 KB each)
  int tid = threadIdx.x;
  int tile = blockIdx.x, b = blockIdx.y;
  int tx0 = (tile & 7)*16, ty0 = (tile >> 3)*8;
  int lane = tid & 63, wid = tid >> 6;

  for (int e = tid; e < 180*16; e += 512){
    int cg = e & 15, p = e >> 4;
    int hr = p/18, wc = p - hr*18;
    int gy = ty0 + hr - 1, gx = tx0 + wc - 1;
    union { short s[8]; bf16x8 v; } u;
    if (((unsigned)gy < P) && ((unsigned)gx < P)){
      if (cg < 8){
        const float* src = y2 + ((size_t)(b*NP) + (size_t)gy*P + gx)*64 + cg*8;
        float4 a = *(const float4*)src, b4 = *(const float4*)(src+4);
        int c = cg*8;
        u.s[0] = f2bf(fmaxf(a.x*stats[c+0]+stats[64+c+0], 0.f));
        u.s[1] = f2bf(fmaxf(a.y*stats[c+1]+stats[64+c+1], 0.f));
        u.s[2] = f2bf(fmaxf(a.z*stats[c+2]+stats[64+c+2], 0.f));
        u.s[3] = f2bf(fmaxf(a.w*stats[c+3]+stats[64+c+3], 0.f));
        u.s[4] = f2bf(fmaxf(b4.x*stats[c+4]+stats[64+c+4], 0.f));
        u.s[5] = f2bf(fmaxf(b4.y*stats[c+5]+stats[64+c+5], 0.f));
        u.s[6] = f2bf(fmaxf(b4.z*stats[c+6]+stats[64+c+6], 0.f));
        u.s[7] = f2bf(fmaxf(b4.w*stats[c+7]+stats[64+c+7], 0.f));
      } else {
        u.v = *(const bf16x8*)(hcl + ((size_t)(b*NP) + (size_t)gy*P + gx)*64 + (cg-8)*8);
      }
    } else {
      #pragma unroll
      for (int j = 0; j < 8; j++) u.s[j] = 0;
    }
    *(bf16x8*)((char*)bs + p*256 + ((cg*16) ^ ((p&7)<<4))) = u.v;
  }

  auto stageA = [&](int c, int bi){
    const short* g = wA + (size_t)c*8192;
    short* l = abuf + bi*8192;
    #pragma unroll
    for (int i = 0; i < 2; i++){
      int unit = wid*2 + i;
      __builtin_amdgcn_global_load_lds(
          (const __attribute__((address_space(1))) unsigned int*)(g + (size_t)(unit*64 + lane)*8),
          (__attribute__((address_space(3))) unsigned int*)(l + (size_t)unit*512),
          16, 0, 0);
    }
  };

  stageA(0, 0);
  stageA(1, 1);
  __syncthreads();   // B staged + chunks 0,1 landed

  int kg = lane >> 4, ln = lane & 15;
  int ct = wid >> 1, nh = wid & 1;
  f32x4 acc[4][4];
  #pragma unroll
  for (int mf = 0; mf < 4; mf++)
    #pragma unroll
    for (int rr = 0; rr < 4; rr++) acc[mf][rr] = (f32x4){0.f,0.f,0.f,0.f};

  for (int c = 0; c < 36; c++){
    int cur = c & 1;
    int tap = c >> 2, cb = c & 3;
    int ky = tap/3, kx = tap - ky*3;
    const short* al = abuf + cur*8192;
    bf16x8 af[4], bf[4];
    #pragma unroll
    for (int mf = 0; mf < 4; mf++)
      af[mf] = *(const bf16x8*)(al + (size_t)(ct*4 + mf)*512 + lane*8);
    #pragma unroll
    for (int rr = 0; rr < 4; rr++){
      int p = (nh*4 + rr + ky)*18 + ln + kx;
      bf[rr] = *(const bf16x8*)((const char*)bs + p*256 + (((cb*64) + kg*16) ^ ((p&7)<<4)));
    }
    asm volatile("s_waitcnt lgkmcnt(0)" ::: "memory");
    __builtin_amdgcn_sched_barrier(0);
    __builtin_amdgcn_s_setprio(1);
    #pragma unroll
    for (int rr = 0; rr < 4; rr++)
      #pragma unroll
      for (int mf = 0; mf < 4; mf++)
        acc[mf][rr] = __builtin_amdgcn_mfma_f32_16x16x32_bf16(af[mf], bf[rr], acc[mf][rr], 0, 0, 0);
    __builtin_amdgcn_s_setprio(0);
    // drain own stage(c+1) loads (issued a full iteration ago -> cheap), then one barrier:
    // post-barrier, all waves' reads of cur are done AND all of chunk c+1 is in LDS.
    asm volatile("s_waitcnt vmcnt(0)" ::: "memory");
    __builtin_amdgcn_sched_barrier(0);
    __builtin_amdgcn_s_barrier();
    __builtin_amdgcn_sched_barrier(0);
    if (c + 2 < 36) stageA(c + 2, cur);   // overlaps next iter's ds_read + MFMA
  }

  #pragma unroll
  for (int mf = 0; mf < 4; mf++){
    int ch = ct*16 + mf*4 + kg;
    float bi = bg[ch], bff = bg[64+ch], bo = bg[128+ch], bgv = bg[192+ch];
    #pragma unroll
    for (int rr = 0; rr < 4; rr++){
      int py = ty0 + nh*4 + rr, px = tx0 + ln;
      size_t pidx = ((size_t)(b*64 + ch))*NP + (size_t)py*P + px;
      f32x4 a = acc[mf][rr];
      float cv = sigmoidf_(a[1]+bff)*c0[pidx] + sigmoidf_(a[0]+bi)*tanhf_(a[3]+bgv);
      float hv = sigmoidf_(a[2]+bo)*tanhf_(cv);
      outh[pidx] = hv;
      outc[pidx] = cv;
    }
  }
}

extern "C" void kernel_launch(void* const* d_in, const int* in_sizes, int n_in,
                              void* d_out, int out_size, void* d_ws, size_t ws_size,
                              hipStream_t stream) {
  const float* x      = (const float*)d_in[0];
  const float* h0     = (const float*)d_in[1];
  const float* c0     = (const float*)d_in[2];
  const float* w_off1 = (const float*)d_in[3];
  const float* b_off1 = (const float*)d_in[4];
  const float* w1     = (const float*)d_in[5];
  const float* g1     = (const float*)d_in[6];
  const float* be1    = (const float*)d_in[7];
  const float* w_off2 = (const float*)d_in[8];
  const float* b_off2 = (const float*)d_in[9];
  const float* w2     = (const float*)d_in[10];
  const float* g2     = (const float*)d_in[11];
  const float* be2    = (const float*)d_in[12];
  const float* wg     = (const float*)d_in[13];
  const float* bg     = (const float*)d_in[14];

  float* ws     = (float*)d_ws;
  float* xpcl   = ws;                          // 2097152 (dead after deform32)
  short* hcl    = (short*)ws;                  // overlays xpcl: 4194304 shorts
  float* y1     = ws + 2097152;                // 4194304
  float* y2     = ws + 6291456;                // 4194304
  float* part   = ws + 10485760;               // 131072
  float* stats1 = ws + 10616832;               // 128
  float* stats2 = ws + 10616960;               // 128
  short* wA     = (short*)(ws + 10617088);     // 294912
  short* wd1T   = wA + 294912;                 // 18432
  short* wd2T   = wd1T + 18432;                // 36864
  short* woT1   = wd2T + 36864;                // 9216
  short* woT2   = woT1 + 9216;                 // 18432

  (void)hipFuncSetAttribute((const void*)gates_mfma_k,
                            hipFuncAttributeMaxDynamicSharedMemorySize, 78848);

  prep_k<<<dim3(256 + 1476), dim3(256), 0, stream>>>(
      x, xpcl, wg, w1, w2, w_off1, w_off2, wA, wd1T, wd2T, woT1, woT2);

  deform_fused_k<32,false><<<dim3(256, BATCH), dim3(256), 0, stream>>>(
      xpcl, stats1, b_off1, woT1, wd1T, y1, part);
  // xpcl dead from here; hcl overlay becomes writable
  aux1_k<<<dim3(64 + 1024), dim3(256), 0, stream>>>(part, g1, be1, stats1, h0, hcl);

  deform_fused_k<64,true><<<dim3(256, BATCH), dim3(256), 0, stream>>>(
      y1, stats1, b_off2, woT2, wd2T, y2, part);
  bnfinal2_k<<<dim3(64), dim3(256), 0, stream>>>(part, g2, be2, stats2);

  float* outh = (float*)d_out;
  float* outc = outh + (size_t)BATCH*64*NP;
  gates_mfma_k<<<dim3(128, BATCH), dim3(512), 78848, stream>>>(
      y2, stats2, hcl, c0, wA, bg, outh, outc);
}